// Round 2
// baseline (458.693 us; speedup 1.0000x reference)
//
#include <hip/hip_runtime.h>

#define B_ 2
#define T_ 2048
#define E_ 1024
#define H_ 16
#define D_ 64
#define DF_ 4096
#define M_ (B_*T_)   // 4096 rows

typedef unsigned short u16;
typedef __attribute__((ext_vector_type(8))) short short8;
typedef __attribute__((ext_vector_type(4))) float f32x4;

__device__ __forceinline__ u16 f2bf(float f) {
  unsigned u = __builtin_bit_cast(unsigned, f);
  u += 0x7FFFu + ((u >> 16) & 1u);   // RNE
  return (u16)(u >> 16);
}

// ---------------- cast fp32 -> bf16 (vectorized x4) ----------------
__global__ __launch_bounds__(256) void cast_bf16_kernel(const float* __restrict__ in,
                                                        u16* __restrict__ out, int n4) {
  int i = blockIdx.x * 256 + threadIdx.x;
  if (i >= n4) return;
  float4 v = ((const float4*)in)[i];
  uint2 r;
  r.x = (unsigned)f2bf(v.x) | ((unsigned)f2bf(v.y) << 16);
  r.y = (unsigned)f2bf(v.z) | ((unsigned)f2bf(v.w) << 16);
  ((uint2*)out)[i] = r;
}

// ---------------- tiled transpose + cast: in[z][r][c] (f32) -> out[(z*C+c)*outld + r] (bf16)
__global__ __launch_bounds__(256) void transpose_cast_kernel(const float* __restrict__ in,
                                                             u16* __restrict__ out,
                                                             int R, int C, int outld) {
  __shared__ float tile[32][33];
  int z = blockIdx.z;
  int c0 = blockIdx.x * 32, r0 = blockIdx.y * 32;
  int tx = threadIdx.x & 31, ty = threadIdx.x >> 5;
  const float* ip = in + (size_t)z * R * C;
#pragma unroll
  for (int i = 0; i < 32; i += 8)
    tile[ty + i][tx] = ip[(size_t)(r0 + ty + i) * C + (c0 + tx)];
  __syncthreads();
#pragma unroll
  for (int i = 0; i < 32; i += 8)
    out[(size_t)(z * C + c0 + ty + i) * outld + (r0 + tx)] = f2bf(tile[tx][ty + i]);
}

// ---------------- bf16 MFMA GEMM: C[M,N] = A[M,K] @ Bt[N,K]^T  ----------------
// 128x128 tile, 4 waves (2x2), BK=32, acc 4x4 16x16 fragments per wave.
template<bool BIAS, bool RELU, bool RES, bool OF32, bool OBF>
__global__ __launch_bounds__(256) void gemm_bt(const u16* __restrict__ A,
                                               const u16* __restrict__ Bt,
                                               int M, int N, int K,
                                               const float* __restrict__ bias,
                                               const float* __restrict__ res,
                                               float* __restrict__ outf,
                                               u16* __restrict__ outb) {
  __shared__ __attribute__((aligned(16))) u16 As[128][40];  // 80B row stride: 16B-aligned
  __shared__ __attribute__((aligned(16))) u16 Bs[128][40];
  int m0 = blockIdx.y * 128, n0 = blockIdx.x * 128;
  int tid = threadIdx.x;
  int lane = tid & 63, w = tid >> 6;
  int wr = w >> 1, wc = w & 1;
  int lg = lane >> 4, lq = lane & 15;
  int sr = tid >> 2, sc = (tid & 3) * 8;

  f32x4 acc[4][4] = {};

  for (int k0 = 0; k0 < K; k0 += 32) {
    __syncthreads();
    *(uint4*)&As[sr][sc]      = *(const uint4*)&A[(size_t)(m0 + sr) * K + k0 + sc];
    *(uint4*)&As[sr + 64][sc] = *(const uint4*)&A[(size_t)(m0 + sr + 64) * K + k0 + sc];
    *(uint4*)&Bs[sr][sc]      = *(const uint4*)&Bt[(size_t)(n0 + sr) * K + k0 + sc];
    *(uint4*)&Bs[sr + 64][sc] = *(const uint4*)&Bt[(size_t)(n0 + sr + 64) * K + k0 + sc];
    __syncthreads();
    short8 af[4], bf[4];
#pragma unroll
    for (int m = 0; m < 4; m++) af[m] = *(const short8*)&As[wr * 64 + m * 16 + lq][lg * 8];
#pragma unroll
    for (int n = 0; n < 4; n++) bf[n] = *(const short8*)&Bs[wc * 64 + n * 16 + lq][lg * 8];
#pragma unroll
    for (int m = 0; m < 4; m++)
#pragma unroll
      for (int n = 0; n < 4; n++)
        acc[m][n] = __builtin_amdgcn_mfma_f32_16x16x32_bf16(af[m], bf[n], acc[m][n], 0, 0, 0);
  }

#pragma unroll
  for (int m = 0; m < 4; m++)
#pragma unroll
    for (int n = 0; n < 4; n++) {
      int row = m0 + wr * 64 + m * 16 + lg * 4;
      int col = n0 + wc * 64 + n * 16 + lq;
      float bv = BIAS ? bias[col] : 0.f;
#pragma unroll
      for (int r = 0; r < 4; r++) {
        float v = acc[m][n][r];
        if (BIAS) v += bv;
        if (RES)  v += res[(size_t)(row + r) * N + col];
        if (RELU) v = fmaxf(v, 0.f);
        if (OF32) outf[(size_t)(row + r) * N + col] = v;
        if (OBF)  outb[(size_t)(row + r) * N + col] = f2bf(v);
      }
    }
}

// ---------------- causal flash attention, 1 wave / 16-query tile ----------------
// Q,K,V: bf16 [M_, E_] with col = h*64 + d.  Computes S^T = K@Q^T (swapped) so the
// per-query softmax reduce is shfl_xor(16/32) and O^T rescale is lane-uniform.
__global__ __launch_bounds__(64) void attn_kernel(const u16* __restrict__ Qb,
                                                  const u16* __restrict__ Kb,
                                                  const u16* __restrict__ Vb,
                                                  u16* __restrict__ attn) {
  __shared__ __attribute__((aligned(16))) u16 P_lds[32][16];
  int bid = blockIdx.x;
  int qt = bid & 127;          // T_/16 tiles
  int h  = (bid >> 7) & 15;
  int b  = bid >> 11;
  int q0 = qt * 16;
  int lane = threadIdx.x;
  int lg = lane >> 4, lq = lane & 15;

  const size_t rowQ = (size_t)(b * T_ + q0 + lq) * E_ + h * 64;
  short8 qf0 = *(const short8*)&Qb[rowQ + lg * 8];
  short8 qf1 = *(const short8*)&Qb[rowQ + 32 + lg * 8];

  f32x4 o[4] = {};
  float m_run = -__builtin_inff(), l_run = 0.f;
  const int q_abs = q0 + lq;
  const int s_last = q0 + 15;
  const float scale = 0.03125f;  // E_^-0.5 (faithful to reference: C**-0.5)

  for (int s0 = 0; s0 <= s_last; s0 += 32) {
    f32x4 st[2];
#pragma unroll
    for (int t = 0; t < 2; t++) {
      int krow = s0 + t * 16 + lq; if (krow > T_ - 1) krow = T_ - 1;
      const size_t rk = (size_t)(b * T_ + krow) * E_ + h * 64;
      short8 kf0 = *(const short8*)&Kb[rk + lg * 8];
      short8 kf1 = *(const short8*)&Kb[rk + 32 + lg * 8];
      f32x4 c = {};
      c = __builtin_amdgcn_mfma_f32_16x16x32_bf16(kf0, qf0, c, 0, 0, 0);
      c = __builtin_amdgcn_mfma_f32_16x16x32_bf16(kf1, qf1, c, 0, 0, 0);
      st[t] = c;
    }
    // scale + causal mask + tile max
    float tmax = -__builtin_inff();
#pragma unroll
    for (int t = 0; t < 2; t++)
#pragma unroll
      for (int r = 0; r < 4; r++) {
        int s_abs = s0 + t * 16 + lg * 4 + r;
        float v = st[t][r] * scale;
        v = (s_abs > q_abs) ? -__builtin_inff() : v;
        st[t][r] = v;
        tmax = fmaxf(tmax, v);
      }
    tmax = fmaxf(tmax, __shfl_xor(tmax, 16));
    tmax = fmaxf(tmax, __shfl_xor(tmax, 32));
    float newm = fmaxf(m_run, tmax);
    float fac = __expf(m_run - newm);
    m_run = newm;
    float psum = 0.f;
#pragma unroll
    for (int t = 0; t < 2; t++)
#pragma unroll
      for (int r = 0; r < 4; r++) {
        float p = __expf(st[t][r] - newm);
        st[t][r] = p;
        psum += p;
      }
    psum += __shfl_xor(psum, 16);
    psum += __shfl_xor(psum, 32);
    l_run = l_run * fac + psum;
#pragma unroll
    for (int c = 0; c < 4; c++) o[c] *= fac;

    // P (C-layout) -> LDS -> B-fragment layout
    __syncthreads();
#pragma unroll
    for (int t = 0; t < 2; t++)
#pragma unroll
      for (int r = 0; r < 4; r++)
        P_lds[t * 16 + lg * 4 + r][lq] = f2bf(st[t][r]);
    __syncthreads();
    short8 pf;
#pragma unroll
    for (int v = 0; v < 8; v++) pf[v] = (short)P_lds[lg * 8 + v][lq];

    // O^T += V^T @ P^T   (A = V^T chunk [16d x 32s], B = P^T)
#pragma unroll
    for (int c = 0; c < 4; c++) {
      short8 vf;
#pragma unroll
      for (int v = 0; v < 8; v++) {
        int srow = s0 + lg * 8 + v; if (srow > T_ - 1) srow = T_ - 1;
        vf[v] = (short)Vb[(size_t)(b * T_ + srow) * E_ + h * 64 + c * 16 + lq];
      }
      o[c] = __builtin_amdgcn_mfma_f32_16x16x32_bf16(vf, pf, o[c], 0, 0, 0);
    }
  }

  float inv = 1.f / l_run;
  const size_t orow = (size_t)(b * T_ + q0 + lq) * E_ + h * 64;
#pragma unroll
  for (int c = 0; c < 4; c++) {
    uint2 r;
    r.x = (unsigned)f2bf(o[c][0] * inv) | ((unsigned)f2bf(o[c][1] * inv) << 16);
    r.y = (unsigned)f2bf(o[c][2] * inv) | ((unsigned)f2bf(o[c][3] * inv) << 16);
    *(uint2*)&attn[orow + c * 16 + lg * 4] = r;
  }
}

// ---------------- launch ----------------
extern "C" void kernel_launch(void* const* d_in, const int* in_sizes, int n_in,
                              void* d_out, int out_size, void* d_ws, size_t ws_size,
                              hipStream_t stream) {
  const float* x  = (const float*)d_in[0];
  const float* Wq = (const float*)d_in[1];
  const float* Wk = (const float*)d_in[2];
  const float* Wv = (const float*)d_in[3];
  const float* Wo = (const float*)d_in[4];
  const float* bo = (const float*)d_in[5];
  const float* W1 = (const float*)d_in[6];
  const float* b1 = (const float*)d_in[7];
  const float* W2 = (const float*)d_in[8];
  const float* b2 = (const float*)d_in[9];
  float* out = (float*)d_out;

  const size_t MB = 1048576;
  char* ws = (char*)d_ws;
  u16* xb   = (u16*)(ws + 0);          // 8MB, aliased by x1b after it is dead
  u16* WqT  = (u16*)(ws + 8  * MB);    // 2MB
  u16* WkT  = (u16*)(ws + 10 * MB);    // 2MB
  u16* WvT  = (u16*)(ws + 12 * MB);    // 2MB
  u16* WoT  = (u16*)(ws + 14 * MB);    // 2MB
  u16* W1T  = (u16*)(ws + 16 * MB);    // 8MB
  u16* W2T  = (u16*)(ws + 24 * MB);    // 8MB
  u16* Qb   = (u16*)(ws + 32 * MB);    // 8MB, aliased by hbuf later
  u16* Kb   = (u16*)(ws + 40 * MB);    // 8MB, aliased by hbuf later
  u16* Vb   = (u16*)(ws + 48 * MB);    // 8MB, aliased by hbuf later
  u16* attn = (u16*)(ws + 56 * MB);    // 8MB, aliased by hbuf later
  float* x1 = (float*)(ws + 64 * MB);  // 16MB
  u16* x1b  = (u16*)(ws + 0);          // alias xb (dead after QKV GEMMs)
  u16* hbuf = (u16*)(ws + 32 * MB);    // 32MB alias Qb..attn (dead after proj GEMM)

  // prep: cast + weight transposes to [N][K] bf16
  cast_bf16_kernel<<<(M_ * E_ / 4 + 255) / 256, 256, 0, stream>>>(x, xb, M_ * E_ / 4);
  transpose_cast_kernel<<<dim3(2, 32, 16),  256, 0, stream>>>(Wq, WqT, E_, D_, E_);
  transpose_cast_kernel<<<dim3(2, 32, 16),  256, 0, stream>>>(Wk, WkT, E_, D_, E_);
  transpose_cast_kernel<<<dim3(2, 32, 16),  256, 0, stream>>>(Wv, WvT, E_, D_, E_);
  transpose_cast_kernel<<<dim3(32, 32, 1),  256, 0, stream>>>(Wo, WoT, E_, E_, E_);
  transpose_cast_kernel<<<dim3(128, 32, 1), 256, 0, stream>>>(W1, W1T, E_, DF_, E_);
  transpose_cast_kernel<<<dim3(32, 128, 1), 256, 0, stream>>>(W2, W2T, DF_, E_, DF_);

  dim3 gE(E_ / 128, M_ / 128);
  gemm_bt<false,false,false,false,true><<<gE, 256, 0, stream>>>(xb, WqT, M_, E_, E_, nullptr, nullptr, nullptr, Qb);
  gemm_bt<false,false,false,false,true><<<gE, 256, 0, stream>>>(xb, WkT, M_, E_, E_, nullptr, nullptr, nullptr, Kb);
  gemm_bt<false,false,false,false,true><<<gE, 256, 0, stream>>>(xb, WvT, M_, E_, E_, nullptr, nullptr, nullptr, Vb);

  attn_kernel<<<B_ * H_ * (T_ / 16), 64, 0, stream>>>(Qb, Kb, Vb, attn);

  // x1 = x + attn @ Wo + bo   (fp32 + bf16 mirror)
  gemm_bt<true,false,true,true,true><<<gE, 256, 0, stream>>>(attn, WoT, M_, E_, E_, bo, x, x1, x1b);
  // h = relu(x1 @ W1 + b1)
  dim3 gF(DF_ / 128, M_ / 128);
  gemm_bt<true,true,false,false,true><<<gF, 256, 0, stream>>>(x1b, W1T, M_, DF_, E_, b1, nullptr, nullptr, hbuf);
  // out = x1 + h @ W2 + b2
  gemm_bt<true,false,true,true,false><<<gE, 256, 0, stream>>>(hbuf, W2T, M_, E_, DF_, b2, x1, out, nullptr);
}

// Round 3
// 378.140 us; speedup vs baseline: 1.2130x; 1.2130x over previous
//
#include <hip/hip_runtime.h>

#define B_ 2
#define T_ 2048
#define E_ 1024
#define H_ 16
#define D_ 64
#define DF_ 4096
#define M_ (B_*T_)   // 4096 rows

typedef unsigned short u16;
typedef __attribute__((ext_vector_type(8))) short short8;
typedef __attribute__((ext_vector_type(4))) float f32x4;

__device__ __forceinline__ u16 f2bf(float f) {
  unsigned u = __builtin_bit_cast(unsigned, f);
  u += 0x7FFFu + ((u >> 16) & 1u);   // RNE
  return (u16)(u >> 16);
}

// ---------------- cast fp32 -> bf16 (vectorized x4) ----------------
__global__ __launch_bounds__(256) void cast_bf16_kernel(const float* __restrict__ in,
                                                        u16* __restrict__ out, int n4) {
  int i = blockIdx.x * 256 + threadIdx.x;
  if (i >= n4) return;
  float4 v = ((const float4*)in)[i];
  uint2 r;
  r.x = (unsigned)f2bf(v.x) | ((unsigned)f2bf(v.y) << 16);
  r.y = (unsigned)f2bf(v.z) | ((unsigned)f2bf(v.w) << 16);
  ((uint2*)out)[i] = r;
}

// ---------------- tiled transpose + cast: in[z][r][c] (f32) -> out[(z*C+c)*outld + r] (bf16)
__global__ __launch_bounds__(256) void transpose_cast_kernel(const float* __restrict__ in,
                                                             u16* __restrict__ out,
                                                             int R, int C, int outld) {
  __shared__ float tile[32][33];
  int z = blockIdx.z;
  int c0 = blockIdx.x * 32, r0 = blockIdx.y * 32;
  int tx = threadIdx.x & 31, ty = threadIdx.x >> 5;
  const float* ip = in + (size_t)z * R * C;
#pragma unroll
  for (int i = 0; i < 32; i += 8)
    tile[ty + i][tx] = ip[(size_t)(r0 + ty + i) * C + (c0 + tx)];
  __syncthreads();
#pragma unroll
  for (int i = 0; i < 32; i += 8)
    out[(size_t)(z * C + c0 + ty + i) * outld + (r0 + tx)] = f2bf(tile[tx][ty + i]);
}

// ---------------- u16 transpose: in[R][C] -> out[C][R], 64x64 tiles ----------------
__global__ __launch_bounds__(256) void transpose_u16_kernel(const u16* __restrict__ in,
                                                            u16* __restrict__ out,
                                                            int R, int C) {
  __shared__ __attribute__((aligned(16))) u16 tile[64][72];
  int c0 = blockIdx.x * 64, r0 = blockIdx.y * 64;
  int t = threadIdx.x;
  int tr = t >> 4, tc = (t & 15) * 4;
#pragma unroll
  for (int i = 0; i < 4; i++)
    *(uint2*)&tile[tr + i * 16][tc] = *(const uint2*)&in[(size_t)(r0 + tr + i * 16) * C + c0 + tc];
  __syncthreads();
  int rr = (t & 15) * 4, cc0 = t >> 4;
#pragma unroll
  for (int i = 0; i < 4; i++) {
    int cc = cc0 + i * 16;
    u16 a = tile[rr][cc], b = tile[rr + 1][cc], c = tile[rr + 2][cc], d = tile[rr + 3][cc];
    uint2 v;
    v.x = (unsigned)a | ((unsigned)b << 16);
    v.y = (unsigned)c | ((unsigned)d << 16);
    *(uint2*)&out[(size_t)(c0 + cc) * R + r0 + rr] = v;
  }
}

// ---------------- bf16 MFMA GEMM: C[M,N] = A[M,K] @ Bt[N,K]^T  ----------------
// 128x128 tile, 4 waves (2x2), BK=32, acc 4x4 16x16 fragments per wave.
template<bool BIAS, bool RELU, bool RES, bool OF32, bool OBF>
__global__ __launch_bounds__(256) void gemm_bt(const u16* __restrict__ A,
                                               const u16* __restrict__ Bt,
                                               int M, int N, int K,
                                               const float* __restrict__ bias,
                                               const float* __restrict__ res,
                                               float* __restrict__ outf,
                                               u16* __restrict__ outb) {
  __shared__ __attribute__((aligned(16))) u16 As[128][40];  // 80B row stride: 16B-aligned
  __shared__ __attribute__((aligned(16))) u16 Bs[128][40];
  int m0 = blockIdx.y * 128, n0 = blockIdx.x * 128;
  int tid = threadIdx.x;
  int lane = tid & 63, w = tid >> 6;
  int wr = w >> 1, wc = w & 1;
  int lg = lane >> 4, lq = lane & 15;
  int sr = tid >> 2, sc = (tid & 3) * 8;

  f32x4 acc[4][4] = {};

  for (int k0 = 0; k0 < K; k0 += 32) {
    __syncthreads();
    *(uint4*)&As[sr][sc]      = *(const uint4*)&A[(size_t)(m0 + sr) * K + k0 + sc];
    *(uint4*)&As[sr + 64][sc] = *(const uint4*)&A[(size_t)(m0 + sr + 64) * K + k0 + sc];
    *(uint4*)&Bs[sr][sc]      = *(const uint4*)&Bt[(size_t)(n0 + sr) * K + k0 + sc];
    *(uint4*)&Bs[sr + 64][sc] = *(const uint4*)&Bt[(size_t)(n0 + sr + 64) * K + k0 + sc];
    __syncthreads();
    short8 af[4], bf[4];
#pragma unroll
    for (int m = 0; m < 4; m++) af[m] = *(const short8*)&As[wr * 64 + m * 16 + lq][lg * 8];
#pragma unroll
    for (int n = 0; n < 4; n++) bf[n] = *(const short8*)&Bs[wc * 64 + n * 16 + lq][lg * 8];
#pragma unroll
    for (int m = 0; m < 4; m++)
#pragma unroll
      for (int n = 0; n < 4; n++)
        acc[m][n] = __builtin_amdgcn_mfma_f32_16x16x32_bf16(af[m], bf[n], acc[m][n], 0, 0, 0);
  }

#pragma unroll
  for (int m = 0; m < 4; m++)
#pragma unroll
    for (int n = 0; n < 4; n++) {
      int row = m0 + wr * 64 + m * 16 + lg * 4;
      int col = n0 + wc * 64 + n * 16 + lq;
      float bv = BIAS ? bias[col] : 0.f;
#pragma unroll
      for (int r = 0; r < 4; r++) {
        float v = acc[m][n][r];
        if (BIAS) v += bv;
        if (RES)  v += res[(size_t)(row + r) * N + col];
        if (RELU) v = fmaxf(v, 0.f);
        if (OF32) outf[(size_t)(row + r) * N + col] = v;
        if (OBF)  outb[(size_t)(row + r) * N + col] = f2bf(v);
      }
    }
}

// ---------------- causal flash attention v2: 4 waves / 64-query block ----------------
// Q,K: bf16 [M_, E_] (col = h*64+d).  Vt: bf16 [E_][M_] = Vt[(h*64+d)][b*T_+s].
// K,V tiles (KVBLK=64) staged in LDS once per block, shared by 4 waves.
// Each wave: 16 queries, swapped QK^T (S^T = K@Q^T) -> softmax reduce via shfl 16/32.
__global__ __launch_bounds__(256) void attn_kernel(const u16* __restrict__ Qb,
                                                   const u16* __restrict__ Kb,
                                                   const u16* __restrict__ Vt,
                                                   u16* __restrict__ attn) {
  __shared__ __attribute__((aligned(16))) u16 Ks[64][72];
  __shared__ __attribute__((aligned(16))) u16 Vs[64][72];   // rows=d, cols=s
  __shared__ u16 Ps[4][64][20];                             // per-wave P^T [s][q]
  int bid = blockIdx.x;
  int j  = bid & 31;
  int qt = (j & 1) ? (31 - (j >> 1)) : (j >> 1);  // heavy/light pairing
  int h  = (bid >> 5) & 15;
  int b  = bid >> 9;
  int tid = threadIdx.x;
  int lane = tid & 63, w = tid >> 6;
  int lg = lane >> 4, lq = lane & 15;
  int q_first = qt * 64 + w * 16;
  int q_abs = q_first + lq;

  const size_t rowQ = (size_t)(b * T_ + q_first + lq) * E_ + h * 64;
  short8 qf0 = *(const short8*)&Qb[rowQ + lg * 8];
  short8 qf1 = *(const short8*)&Qb[rowQ + 32 + lg * 8];

  const u16* Kbase  = Kb + (size_t)(b * T_) * E_ + h * 64;
  const u16* Vtbase = Vt + (size_t)(h * 64) * M_ + b * T_;

  // staging decomposition: 512 uint4 per tile per matrix; 2 per thread
  int u0 = tid, u1 = tid + 256;
  int r0s = u0 >> 3, c0s = (u0 & 7) * 8;
  int r1s = u1 >> 3, c1s = (u1 & 7) * 8;

  f32x4 o[4] = {};
  float m_run = -__builtin_inff(), l_run = 0.f;
  const float scale = 0.03125f;  // E_^-0.5 (faithful: reference scales by C**-0.5)
  const int s_end = qt * 64 + 63;

  for (int s0 = 0; s0 <= s_end; s0 += 64) {
    __syncthreads();
    *(uint4*)&Ks[r0s][c0s] = *(const uint4*)&Kbase[(size_t)(s0 + r0s) * E_ + c0s];
    *(uint4*)&Ks[r1s][c1s] = *(const uint4*)&Kbase[(size_t)(s0 + r1s) * E_ + c1s];
    *(uint4*)&Vs[r0s][c0s] = *(const uint4*)&Vtbase[(size_t)r0s * M_ + s0 + c0s];
    *(uint4*)&Vs[r1s][c1s] = *(const uint4*)&Vtbase[(size_t)r1s * M_ + s0 + c1s];
    __syncthreads();
    if (s0 > q_first + 15) continue;   // tile fully masked for this wave (uniform)

    // --- S^T = K @ Q^T over 4 sub-tiles of 16 keys ---
    f32x4 st[4];
#pragma unroll
    for (int t2 = 0; t2 < 4; t2++) {
      short8 kf0 = *(const short8*)&Ks[t2 * 16 + lq][lg * 8];
      short8 kf1 = *(const short8*)&Ks[t2 * 16 + lq][32 + lg * 8];
      f32x4 c = {};
      c = __builtin_amdgcn_mfma_f32_16x16x32_bf16(kf0, qf0, c, 0, 0, 0);
      c = __builtin_amdgcn_mfma_f32_16x16x32_bf16(kf1, qf1, c, 0, 0, 0);
      st[t2] = c;
    }
    // --- scale + causal mask + tile max ---
    float tmax = -__builtin_inff();
#pragma unroll
    for (int t2 = 0; t2 < 4; t2++)
#pragma unroll
      for (int r = 0; r < 4; r++) {
        int s_abs = s0 + t2 * 16 + lg * 4 + r;
        float v = st[t2][r] * scale;
        v = (s_abs > q_abs) ? -__builtin_inff() : v;
        st[t2][r] = v;
        tmax = fmaxf(tmax, v);
      }
    tmax = fmaxf(tmax, __shfl_xor(tmax, 16));
    tmax = fmaxf(tmax, __shfl_xor(tmax, 32));
    float newm = fmaxf(m_run, tmax);
    float fac = __expf(m_run - newm);
    m_run = newm;
    float psum = 0.f;
#pragma unroll
    for (int t2 = 0; t2 < 4; t2++)
#pragma unroll
      for (int r = 0; r < 4; r++) {
        float p = __expf(st[t2][r] - newm);
        st[t2][r] = p;
        psum += p;
      }
    psum += __shfl_xor(psum, 16);
    psum += __shfl_xor(psum, 32);
    l_run = l_run * fac + psum;
#pragma unroll
    for (int c = 0; c < 4; c++) o[c] *= fac;

    // --- P (C-layout) -> per-wave LDS -> B-fragment layout ---
#pragma unroll
    for (int t2 = 0; t2 < 4; t2++)
#pragma unroll
      for (int r = 0; r < 4; r++)
        Ps[w][t2 * 16 + lg * 4 + r][lq] = f2bf(st[t2][r]);

    // --- O^T += V^T @ P^T  (2 k-chunks of 32 keys) ---
#pragma unroll
    for (int ks = 0; ks < 2; ks++) {
      short8 pf;
#pragma unroll
      for (int v = 0; v < 8; v++) pf[v] = (short)Ps[w][ks * 32 + lg * 8 + v][lq];
#pragma unroll
      for (int c = 0; c < 4; c++) {
        short8 vf = *(const short8*)&Vs[c * 16 + lq][ks * 32 + lg * 8];
        o[c] = __builtin_amdgcn_mfma_f32_16x16x32_bf16(vf, pf, o[c], 0, 0, 0);
      }
    }
  }

  float inv = 1.f / l_run;
  const size_t orow = (size_t)(b * T_ + q_first + lq) * E_ + h * 64;
#pragma unroll
  for (int c = 0; c < 4; c++) {
    uint2 r;
    r.x = (unsigned)f2bf(o[c][0] * inv) | ((unsigned)f2bf(o[c][1] * inv) << 16);
    r.y = (unsigned)f2bf(o[c][2] * inv) | ((unsigned)f2bf(o[c][3] * inv) << 16);
    *(uint2*)&attn[orow + c * 16 + lg * 4] = r;
  }
}

// ---------------- launch ----------------
extern "C" void kernel_launch(void* const* d_in, const int* in_sizes, int n_in,
                              void* d_out, int out_size, void* d_ws, size_t ws_size,
                              hipStream_t stream) {
  const float* x  = (const float*)d_in[0];
  const float* Wq = (const float*)d_in[1];
  const float* Wk = (const float*)d_in[2];
  const float* Wv = (const float*)d_in[3];
  const float* Wo = (const float*)d_in[4];
  const float* bo = (const float*)d_in[5];
  const float* W1 = (const float*)d_in[6];
  const float* b1 = (const float*)d_in[7];
  const float* W2 = (const float*)d_in[8];
  const float* b2 = (const float*)d_in[9];
  float* out = (float*)d_out;

  const size_t MB = 1048576;
  char* ws = (char*)d_ws;
  u16* xb   = (u16*)(ws + 0);          // 8MB, aliased by x1b after it is dead
  u16* WqT  = (u16*)(ws + 8  * MB);    // 2MB
  u16* WkT  = (u16*)(ws + 10 * MB);    // 2MB
  u16* WvT  = (u16*)(ws + 12 * MB);    // 2MB
  u16* WoT  = (u16*)(ws + 14 * MB);    // 2MB
  u16* W1T  = (u16*)(ws + 16 * MB);    // 8MB
  u16* W2T  = (u16*)(ws + 24 * MB);    // 8MB
  u16* Qb   = (u16*)(ws + 32 * MB);    // 8MB, aliased by hbuf later
  u16* Kb   = (u16*)(ws + 40 * MB);    // 8MB, aliased by hbuf later
  u16* Vb   = (u16*)(ws + 48 * MB);    // 8MB, aliased by hbuf later
  u16* attn = (u16*)(ws + 56 * MB);    // 8MB, aliased by hbuf later
  float* x1 = (float*)(ws + 64 * MB);  // 16MB (x1 written AFTER attn consumed Vt)
  u16* Vtb  = (u16*)(ws + 64 * MB);    // 8MB, overlaps x1 (dead before x1 written)
  u16* x1b  = (u16*)(ws + 0);          // alias xb (dead after QKV GEMMs)
  u16* hbuf = (u16*)(ws + 32 * MB);    // 32MB alias Qb..attn (dead after proj GEMM)

  // prep: cast + weight transposes to [N][K] bf16
  cast_bf16_kernel<<<(M_ * E_ / 4 + 255) / 256, 256, 0, stream>>>(x, xb, M_ * E_ / 4);
  transpose_cast_kernel<<<dim3(2, 32, 16),  256, 0, stream>>>(Wq, WqT, E_, D_, E_);
  transpose_cast_kernel<<<dim3(2, 32, 16),  256, 0, stream>>>(Wk, WkT, E_, D_, E_);
  transpose_cast_kernel<<<dim3(2, 32, 16),  256, 0, stream>>>(Wv, WvT, E_, D_, E_);
  transpose_cast_kernel<<<dim3(32, 32, 1),  256, 0, stream>>>(Wo, WoT, E_, E_, E_);
  transpose_cast_kernel<<<dim3(128, 32, 1), 256, 0, stream>>>(W1, W1T, E_, DF_, E_);
  transpose_cast_kernel<<<dim3(32, 128, 1), 256, 0, stream>>>(W2, W2T, DF_, E_, DF_);

  dim3 gE(E_ / 128, M_ / 128);
  gemm_bt<false,false,false,false,true><<<gE, 256, 0, stream>>>(xb, WqT, M_, E_, E_, nullptr, nullptr, nullptr, Qb);
  gemm_bt<false,false,false,false,true><<<gE, 256, 0, stream>>>(xb, WkT, M_, E_, E_, nullptr, nullptr, nullptr, Kb);
  gemm_bt<false,false,false,false,true><<<gE, 256, 0, stream>>>(xb, WvT, M_, E_, E_, nullptr, nullptr, nullptr, Vb);

  // V -> V^T  ([M][E] -> [E][M])
  transpose_u16_kernel<<<dim3(E_ / 64, M_ / 64), 256, 0, stream>>>(Vb, Vtb, M_, E_);

  attn_kernel<<<B_ * H_ * (T_ / 64), 256, 0, stream>>>(Qb, Kb, Vtb, attn);

  // x1 = x + attn @ Wo + bo   (fp32 + bf16 mirror)
  gemm_bt<true,false,true,true,true><<<gE, 256, 0, stream>>>(attn, WoT, M_, E_, E_, bo, x, x1, x1b);
  // h = relu(x1 @ W1 + b1)
  dim3 gF(DF_ / 128, M_ / 128);
  gemm_bt<true,true,false,false,true><<<gF, 256, 0, stream>>>(x1b, W1T, M_, DF_, E_, b1, nullptr, nullptr, hbuf);
  // out = x1 + h @ W2 + b2
  gemm_bt<true,false,true,true,false><<<gE, 256, 0, stream>>>(hbuf, W2T, M_, E_, DF_, b2, x1, out, nullptr);
}

// Round 4
// 374.319 us; speedup vs baseline: 1.2254x; 1.0102x over previous
//
#include <hip/hip_runtime.h>

#define B_ 2
#define T_ 2048
#define E_ 1024
#define H_ 16
#define D_ 64
#define DF_ 4096
#define M_ (B_*T_)   // 4096 rows

typedef unsigned short u16;
typedef __attribute__((ext_vector_type(8))) short short8;
typedef __attribute__((ext_vector_type(4))) float f32x4;

__device__ __forceinline__ u16 f2bf(float f) {
  unsigned u = __builtin_bit_cast(unsigned, f);
  u += 0x7FFFu + ((u >> 16) & 1u);   // RNE
  return (u16)(u >> 16);
}

// async global->LDS DMA, 16B per lane; LDS dest = wave-uniform base + lane*16
__device__ __forceinline__ void gload_lds16(const u16* g, u16* l) {
  __builtin_amdgcn_global_load_lds((const __attribute__((address_space(1))) void*)g,
                                   (__attribute__((address_space(3))) void*)l, 16, 0, 0);
}

// ---------------- cast fp32 -> bf16 (vectorized x4) ----------------
__global__ __launch_bounds__(256) void cast_bf16_kernel(const float* __restrict__ in,
                                                        u16* __restrict__ out, int n4) {
  int i = blockIdx.x * 256 + threadIdx.x;
  if (i >= n4) return;
  float4 v = ((const float4*)in)[i];
  uint2 r;
  r.x = (unsigned)f2bf(v.x) | ((unsigned)f2bf(v.y) << 16);
  r.y = (unsigned)f2bf(v.z) | ((unsigned)f2bf(v.w) << 16);
  ((uint2*)out)[i] = r;
}

// ---------------- tiled transpose + cast: in[z][r][c] (f32) -> out[(z*C+c)*outld + r] (bf16)
__global__ __launch_bounds__(256) void transpose_cast_kernel(const float* __restrict__ in,
                                                             u16* __restrict__ out,
                                                             int R, int C, int outld) {
  __shared__ float tile[32][33];
  int z = blockIdx.z;
  int c0 = blockIdx.x * 32, r0 = blockIdx.y * 32;
  int tx = threadIdx.x & 31, ty = threadIdx.x >> 5;
  const float* ip = in + (size_t)z * R * C;
#pragma unroll
  for (int i = 0; i < 32; i += 8)
    tile[ty + i][tx] = ip[(size_t)(r0 + ty + i) * C + (c0 + tx)];
  __syncthreads();
#pragma unroll
  for (int i = 0; i < 32; i += 8)
    out[(size_t)(z * C + c0 + ty + i) * outld + (r0 + tx)] = f2bf(tile[tx][ty + i]);
}

// ---------------- u16 transpose: in[R][C] -> out[C][R], 64x64 tiles ----------------
__global__ __launch_bounds__(256) void transpose_u16_kernel(const u16* __restrict__ in,
                                                            u16* __restrict__ out,
                                                            int R, int C) {
  __shared__ __attribute__((aligned(16))) u16 tile[64][72];
  int c0 = blockIdx.x * 64, r0 = blockIdx.y * 64;
  int t = threadIdx.x;
  int tr = t >> 4, tc = (t & 15) * 4;
#pragma unroll
  for (int i = 0; i < 4; i++)
    *(uint2*)&tile[tr + i * 16][tc] = *(const uint2*)&in[(size_t)(r0 + tr + i * 16) * C + c0 + tc];
  __syncthreads();
  int rr = (t & 15) * 4, cc0 = t >> 4;
#pragma unroll
  for (int i = 0; i < 4; i++) {
    int cc = cc0 + i * 16;
    u16 a = tile[rr][cc], b = tile[rr + 1][cc], c = tile[rr + 2][cc], d = tile[rr + 3][cc];
    uint2 v;
    v.x = (unsigned)a | ((unsigned)b << 16);
    v.y = (unsigned)c | ((unsigned)d << 16);
    *(uint2*)&out[(size_t)(c0 + cc) * R + r0 + rr] = v;
  }
}

// ---------------- bf16 MFMA GEMM: C[M,N] = A[M,K] @ Bt[N,K]^T  ----------------
// m97 structure: 128x128 tile, 4 waves (2x2), BK=32, LINEAR LDS tiles staged via
// global_load_lds width=16 (wave-uniform LDS dest + per-lane global src).
template<bool BIAS, bool RELU, bool RES, bool OF32, bool OBF>
__global__ __launch_bounds__(256) void gemm_bt(const u16* __restrict__ A,
                                               const u16* __restrict__ Bt,
                                               int M, int N, int K,
                                               const float* __restrict__ bias,
                                               const float* __restrict__ res,
                                               float* __restrict__ outf,
                                               u16* __restrict__ outb) {
  __shared__ __attribute__((aligned(16))) u16 As[128][32];  // linear (DMA-written)
  __shared__ __attribute__((aligned(16))) u16 Bs[128][32];
  int m0 = blockIdx.y * 128, n0 = blockIdx.x * 128;
  int tid = threadIdx.x;
  int lane = tid & 63, w = tid >> 6;
  int wr = w >> 1, wc = w & 1;
  int lg = lane >> 4, lq = lane & 15;

  // staging map: wave w owns tile rows [w*32, w*32+32), two 16-row chunks of 1024B.
  // chunk lane l -> row l/4, u16 col (l&3)*8  (matches linear LDS lane*16B order)
  int srow = lane >> 2;
  int scol = (lane & 3) * 8;
  const u16* aSrc0 = &A [(size_t)(m0 + w * 32 +      srow) * K + scol];
  const u16* aSrc1 = &A [(size_t)(m0 + w * 32 + 16 + srow) * K + scol];
  const u16* bSrc0 = &Bt[(size_t)(n0 + w * 32 +      srow) * K + scol];
  const u16* bSrc1 = &Bt[(size_t)(n0 + w * 32 + 16 + srow) * K + scol];
  u16* aDst0 = &As[w * 32][0];
  u16* aDst1 = &As[w * 32 + 16][0];
  u16* bDst0 = &Bs[w * 32][0];
  u16* bDst1 = &Bs[w * 32 + 16][0];

  f32x4 acc[4][4] = {};

  for (int k0 = 0; k0 < K; k0 += 32) {
    __syncthreads();                 // previous iter's fragment reads complete
    gload_lds16(aSrc0 + k0, aDst0);
    gload_lds16(aSrc1 + k0, aDst1);
    gload_lds16(bSrc0 + k0, bDst0);
    gload_lds16(bSrc1 + k0, bDst1);
    __syncthreads();                 // drains vmcnt -> staged data visible
    short8 af[4], bf[4];
#pragma unroll
    for (int m = 0; m < 4; m++) af[m] = *(const short8*)&As[wr * 64 + m * 16 + lq][lg * 8];
#pragma unroll
    for (int n = 0; n < 4; n++) bf[n] = *(const short8*)&Bs[wc * 64 + n * 16 + lq][lg * 8];
#pragma unroll
    for (int m = 0; m < 4; m++)
#pragma unroll
      for (int n = 0; n < 4; n++)
        acc[m][n] = __builtin_amdgcn_mfma_f32_16x16x32_bf16(af[m], bf[n], acc[m][n], 0, 0, 0);
  }

#pragma unroll
  for (int m = 0; m < 4; m++)
#pragma unroll
    for (int n = 0; n < 4; n++) {
      int row = m0 + wr * 64 + m * 16 + lg * 4;
      int col = n0 + wc * 64 + n * 16 + lq;
      float bv = BIAS ? bias[col] : 0.f;
#pragma unroll
      for (int r = 0; r < 4; r++) {
        float v = acc[m][n][r];
        if (BIAS) v += bv;
        if (RES)  v += res[(size_t)(row + r) * N + col];
        if (RELU) v = fmaxf(v, 0.f);
        if (OF32) outf[(size_t)(row + r) * N + col] = v;
        if (OBF)  outb[(size_t)(row + r) * N + col] = f2bf(v);
      }
    }
}

// ---------------- causal flash attention v2: 4 waves / 64-query block ----------------
// Q,K: bf16 [M_, E_] (col = h*64+d).  Vt: bf16 [E_][M_] = Vt[(h*64+d)][b*T_+s].
// K,V tiles (KVBLK=64) staged in LDS once per block, shared by 4 waves.
// Each wave: 16 queries, swapped QK^T (S^T = K@Q^T) -> softmax reduce via shfl 16/32.
__global__ __launch_bounds__(256) void attn_kernel(const u16* __restrict__ Qb,
                                                   const u16* __restrict__ Kb,
                                                   const u16* __restrict__ Vt,
                                                   u16* __restrict__ attn) {
  __shared__ __attribute__((aligned(16))) u16 Ks[64][72];
  __shared__ __attribute__((aligned(16))) u16 Vs[64][72];   // rows=d, cols=s
  __shared__ u16 Ps[4][64][20];                             // per-wave P^T [s][q]
  int bid = blockIdx.x;
  int j  = bid & 31;
  int qt = (j & 1) ? (31 - (j >> 1)) : (j >> 1);  // heavy/light pairing
  int h  = (bid >> 5) & 15;
  int b  = bid >> 9;
  int tid = threadIdx.x;
  int lane = tid & 63, w = tid >> 6;
  int lg = lane >> 4, lq = lane & 15;
  int q_first = qt * 64 + w * 16;
  int q_abs = q_first + lq;

  const size_t rowQ = (size_t)(b * T_ + q_first + lq) * E_ + h * 64;
  short8 qf0 = *(const short8*)&Qb[rowQ + lg * 8];
  short8 qf1 = *(const short8*)&Qb[rowQ + 32 + lg * 8];

  const u16* Kbase  = Kb + (size_t)(b * T_) * E_ + h * 64;
  const u16* Vtbase = Vt + (size_t)(h * 64) * M_ + b * T_;

  // staging decomposition: 512 uint4 per tile per matrix; 2 per thread
  int u0 = tid, u1 = tid + 256;
  int r0s = u0 >> 3, c0s = (u0 & 7) * 8;
  int r1s = u1 >> 3, c1s = (u1 & 7) * 8;

  f32x4 o[4] = {};
  float m_run = -__builtin_inff(), l_run = 0.f;
  const float scale = 0.03125f;  // E_^-0.5 (faithful: reference scales by C**-0.5)
  const int s_end = qt * 64 + 63;

  for (int s0 = 0; s0 <= s_end; s0 += 64) {
    __syncthreads();
    *(uint4*)&Ks[r0s][c0s] = *(const uint4*)&Kbase[(size_t)(s0 + r0s) * E_ + c0s];
    *(uint4*)&Ks[r1s][c1s] = *(const uint4*)&Kbase[(size_t)(s0 + r1s) * E_ + c1s];
    *(uint4*)&Vs[r0s][c0s] = *(const uint4*)&Vtbase[(size_t)r0s * M_ + s0 + c0s];
    *(uint4*)&Vs[r1s][c1s] = *(const uint4*)&Vtbase[(size_t)r1s * M_ + s0 + c1s];
    __syncthreads();
    if (s0 > q_first + 15) continue;   // tile fully masked for this wave (uniform)

    // --- S^T = K @ Q^T over 4 sub-tiles of 16 keys ---
    f32x4 st[4];
#pragma unroll
    for (int t2 = 0; t2 < 4; t2++) {
      short8 kf0 = *(const short8*)&Ks[t2 * 16 + lq][lg * 8];
      short8 kf1 = *(const short8*)&Ks[t2 * 16 + lq][32 + lg * 8];
      f32x4 c = {};
      c = __builtin_amdgcn_mfma_f32_16x16x32_bf16(kf0, qf0, c, 0, 0, 0);
      c = __builtin_amdgcn_mfma_f32_16x16x32_bf16(kf1, qf1, c, 0, 0, 0);
      st[t2] = c;
    }
    // --- scale + causal mask + tile max ---
    float tmax = -__builtin_inff();
#pragma unroll
    for (int t2 = 0; t2 < 4; t2++)
#pragma unroll
      for (int r = 0; r < 4; r++) {
        int s_abs = s0 + t2 * 16 + lg * 4 + r;
        float v = st[t2][r] * scale;
        v = (s_abs > q_abs) ? -__builtin_inff() : v;
        st[t2][r] = v;
        tmax = fmaxf(tmax, v);
      }
    tmax = fmaxf(tmax, __shfl_xor(tmax, 16));
    tmax = fmaxf(tmax, __shfl_xor(tmax, 32));
    float newm = fmaxf(m_run, tmax);
    float fac = __expf(m_run - newm);
    m_run = newm;
    float psum = 0.f;
#pragma unroll
    for (int t2 = 0; t2 < 4; t2++)
#pragma unroll
      for (int r = 0; r < 4; r++) {
        float p = __expf(st[t2][r] - newm);
        st[t2][r] = p;
        psum += p;
      }
    psum += __shfl_xor(psum, 16);
    psum += __shfl_xor(psum, 32);
    l_run = l_run * fac + psum;
#pragma unroll
    for (int c = 0; c < 4; c++) o[c] *= fac;

    // --- P (C-layout) -> per-wave LDS -> B-fragment layout ---
#pragma unroll
    for (int t2 = 0; t2 < 4; t2++)
#pragma unroll
      for (int r = 0; r < 4; r++)
        Ps[w][t2 * 16 + lg * 4 + r][lq] = f2bf(st[t2][r]);

    // --- O^T += V^T @ P^T  (2 k-chunks of 32 keys) ---
#pragma unroll
    for (int ks = 0; ks < 2; ks++) {
      short8 pf;
#pragma unroll
      for (int v = 0; v < 8; v++) pf[v] = (short)Ps[w][ks * 32 + lg * 8 + v][lq];
#pragma unroll
      for (int c = 0; c < 4; c++) {
        short8 vf = *(const short8*)&Vs[c * 16 + lq][ks * 32 + lg * 8];
        o[c] = __builtin_amdgcn_mfma_f32_16x16x32_bf16(vf, pf, o[c], 0, 0, 0);
      }
    }
  }

  float inv = 1.f / l_run;
  const size_t orow = (size_t)(b * T_ + q_first + lq) * E_ + h * 64;
#pragma unroll
  for (int c = 0; c < 4; c++) {
    uint2 r;
    r.x = (unsigned)f2bf(o[c][0] * inv) | ((unsigned)f2bf(o[c][1] * inv) << 16);
    r.y = (unsigned)f2bf(o[c][2] * inv) | ((unsigned)f2bf(o[c][3] * inv) << 16);
    *(uint2*)&attn[orow + c * 16 + lg * 4] = r;
  }
}

// ---------------- launch ----------------
extern "C" void kernel_launch(void* const* d_in, const int* in_sizes, int n_in,
                              void* d_out, int out_size, void* d_ws, size_t ws_size,
                              hipStream_t stream) {
  const float* x  = (const float*)d_in[0];
  const float* Wq = (const float*)d_in[1];
  const float* Wk = (const float*)d_in[2];
  const float* Wv = (const float*)d_in[3];
  const float* Wo = (const float*)d_in[4];
  const float* bo = (const float*)d_in[5];
  const float* W1 = (const float*)d_in[6];
  const float* b1 = (const float*)d_in[7];
  const float* W2 = (const float*)d_in[8];
  const float* b2 = (const float*)d_in[9];
  float* out = (float*)d_out;

  const size_t MB = 1048576;
  char* ws = (char*)d_ws;
  u16* xb   = (u16*)(ws + 0);          // 8MB, aliased by x1b after it is dead
  u16* WqT  = (u16*)(ws + 8  * MB);    // 2MB
  u16* WkT  = (u16*)(ws + 10 * MB);    // 2MB
  u16* WvT  = (u16*)(ws + 12 * MB);    // 2MB
  u16* WoT  = (u16*)(ws + 14 * MB);    // 2MB
  u16* W1T  = (u16*)(ws + 16 * MB);    // 8MB
  u16* W2T  = (u16*)(ws + 24 * MB);    // 8MB
  u16* Qb   = (u16*)(ws + 32 * MB);    // 8MB, aliased by hbuf later
  u16* Kb   = (u16*)(ws + 40 * MB);    // 8MB, aliased by hbuf later
  u16* Vb   = (u16*)(ws + 48 * MB);    // 8MB, aliased by hbuf later
  u16* attn = (u16*)(ws + 56 * MB);    // 8MB, aliased by hbuf later
  float* x1 = (float*)(ws + 64 * MB);  // 16MB (x1 written AFTER attn consumed Vt)
  u16* Vtb  = (u16*)(ws + 64 * MB);    // 8MB, overlaps x1 (dead before x1 written)
  u16* x1b  = (u16*)(ws + 0);          // alias xb (dead after QKV GEMMs)
  u16* hbuf = (u16*)(ws + 32 * MB);    // 32MB alias Qb..attn (dead after proj GEMM)

  // prep: cast + weight transposes to [N][K] bf16
  cast_bf16_kernel<<<(M_ * E_ / 4 + 255) / 256, 256, 0, stream>>>(x, xb, M_ * E_ / 4);
  transpose_cast_kernel<<<dim3(2, 32, 16),  256, 0, stream>>>(Wq, WqT, E_, D_, E_);
  transpose_cast_kernel<<<dim3(2, 32, 16),  256, 0, stream>>>(Wk, WkT, E_, D_, E_);
  transpose_cast_kernel<<<dim3(2, 32, 16),  256, 0, stream>>>(Wv, WvT, E_, D_, E_);
  transpose_cast_kernel<<<dim3(32, 32, 1),  256, 0, stream>>>(Wo, WoT, E_, E_, E_);
  transpose_cast_kernel<<<dim3(128, 32, 1), 256, 0, stream>>>(W1, W1T, E_, DF_, E_);
  transpose_cast_kernel<<<dim3(32, 128, 1), 256, 0, stream>>>(W2, W2T, DF_, E_, DF_);

  dim3 gE(E_ / 128, M_ / 128);
  gemm_bt<false,false,false,false,true><<<gE, 256, 0, stream>>>(xb, WqT, M_, E_, E_, nullptr, nullptr, nullptr, Qb);
  gemm_bt<false,false,false,false,true><<<gE, 256, 0, stream>>>(xb, WkT, M_, E_, E_, nullptr, nullptr, nullptr, Kb);
  gemm_bt<false,false,false,false,true><<<gE, 256, 0, stream>>>(xb, WvT, M_, E_, E_, nullptr, nullptr, nullptr, Vb);

  // V -> V^T  ([M][E] -> [E][M])
  transpose_u16_kernel<<<dim3(E_ / 64, M_ / 64), 256, 0, stream>>>(Vb, Vtb, M_, E_);

  attn_kernel<<<B_ * H_ * (T_ / 64), 256, 0, stream>>>(Qb, Kb, Vtb, attn);

  // x1 = x + attn @ Wo + bo   (fp32 + bf16 mirror)
  gemm_bt<true,false,true,true,true><<<gE, 256, 0, stream>>>(attn, WoT, M_, E_, E_, bo, x, x1, x1b);
  // h = relu(x1 @ W1 + b1)
  dim3 gF(DF_ / 128, M_ / 128);
  gemm_bt<true,true,false,false,true><<<gF, 256, 0, stream>>>(x1b, W1T, M_, DF_, E_, b1, nullptr, nullptr, hbuf);
  // out = x1 + h @ W2 + b2
  gemm_bt<true,false,true,true,false><<<gE, 256, 0, stream>>>(hbuf, W2T, M_, E_, DF_, b2, x1, out, nullptr);
}

// Round 5
// 291.655 us; speedup vs baseline: 1.5727x; 1.2834x over previous
//
#include <hip/hip_runtime.h>

#define B_ 2
#define T_ 2048
#define E_ 1024
#define H_ 16
#define D_ 64
#define DF_ 4096
#define M_ (B_*T_)   // 4096 rows
#define NQKV_ 3072   // fused QKV output width

typedef unsigned short u16;
typedef __attribute__((ext_vector_type(8))) short short8;
typedef __attribute__((ext_vector_type(4))) float f32x4;

__device__ __forceinline__ u16 f2bf(float f) {
  unsigned u = __builtin_bit_cast(unsigned, f);
  u += 0x7FFFu + ((u >> 16) & 1u);   // RNE
  return (u16)(u >> 16);
}

// async global->LDS DMA, 16B per lane; LDS dest = wave-uniform base + lane*16
__device__ __forceinline__ void gload_lds16(const u16* g, u16* l) {
  __builtin_amdgcn_global_load_lds((const __attribute__((address_space(1))) void*)g,
                                   (__attribute__((address_space(3))) void*)l, 16, 0, 0);
}

// ---------------- cast fp32 -> bf16 (vectorized x4) ----------------
__global__ __launch_bounds__(256) void cast_bf16_kernel(const float* __restrict__ in,
                                                        u16* __restrict__ out, int n4) {
  int i = blockIdx.x * 256 + threadIdx.x;
  if (i >= n4) return;
  float4 v = ((const float4*)in)[i];
  uint2 r;
  r.x = (unsigned)f2bf(v.x) | ((unsigned)f2bf(v.y) << 16);
  r.y = (unsigned)f2bf(v.z) | ((unsigned)f2bf(v.w) << 16);
  ((uint2*)out)[i] = r;
}

// ---------------- tiled transpose + cast: in[z][r][c] (f32) -> out[(z*C+c)*outld + r] (bf16)
__global__ __launch_bounds__(256) void transpose_cast_kernel(const float* __restrict__ in,
                                                             u16* __restrict__ out,
                                                             int R, int C, int outld) {
  __shared__ float tile[32][33];
  int z = blockIdx.z;
  int c0 = blockIdx.x * 32, r0 = blockIdx.y * 32;
  int tx = threadIdx.x & 31, ty = threadIdx.x >> 5;
  const float* ip = in + (size_t)z * R * C;
#pragma unroll
  for (int i = 0; i < 32; i += 8)
    tile[ty + i][tx] = ip[(size_t)(r0 + ty + i) * C + (c0 + tx)];
  __syncthreads();
#pragma unroll
  for (int i = 0; i < 32; i += 8)
    out[(size_t)(z * C + c0 + ty + i) * outld + (r0 + tx)] = f2bf(tile[tx][ty + i]);
}

// ---------------- u16 transpose: in[R][C] (row stride ldin) -> out[C][R], 64x64 tiles ----
__global__ __launch_bounds__(256) void transpose_u16_kernel(const u16* __restrict__ in,
                                                            u16* __restrict__ out,
                                                            int R, int C, int ldin) {
  __shared__ __attribute__((aligned(16))) u16 tile[64][72];
  int c0 = blockIdx.x * 64, r0 = blockIdx.y * 64;
  int t = threadIdx.x;
  int tr = t >> 4, tc = (t & 15) * 4;
#pragma unroll
  for (int i = 0; i < 4; i++)
    *(uint2*)&tile[tr + i * 16][tc] = *(const uint2*)&in[(size_t)(r0 + tr + i * 16) * ldin + c0 + tc];
  __syncthreads();
  int rr = (t & 15) * 4, cc0 = t >> 4;
#pragma unroll
  for (int i = 0; i < 4; i++) {
    int cc = cc0 + i * 16;
    u16 a = tile[rr][cc], b = tile[rr + 1][cc], c = tile[rr + 2][cc], d = tile[rr + 3][cc];
    uint2 v;
    v.x = (unsigned)a | ((unsigned)b << 16);
    v.y = (unsigned)c | ((unsigned)d << 16);
    *(uint2*)&out[(size_t)(c0 + cc) * R + r0 + rr] = v;
  }
}

// ---------------- bf16 MFMA GEMM: C[M,N] = A[M,K] @ Bt[N,K]^T ----------------
// TM x 128 tile, 4 waves (2x2), BK=32, DOUBLE-BUFFERED linear LDS staged via
// global_load_lds w=16; 2-phase pipeline: prefetch k+1 before computing k,
// ONE barrier per K-step (syncthreads drains vmcnt -> prefetch visible).
template<int TM, bool BIAS, bool RELU, bool RES, bool OF32, bool OBF>
__global__ __launch_bounds__(256, 2) void gemm_bt(const u16* __restrict__ A,
                                                  const u16* __restrict__ Bt,
                                                  int M, int N, int K,
                                                  const float* __restrict__ bias,
                                                  const float* __restrict__ res,
                                                  float* __restrict__ outf,
                                                  u16* __restrict__ outb) {
  constexpr int MF = TM / 32;   // m-fragments per wave
  __shared__ __attribute__((aligned(16))) u16 As[2][TM][32];
  __shared__ __attribute__((aligned(16))) u16 Bs[2][128][32];
  int m0 = blockIdx.y * TM, n0 = blockIdx.x * 128;
  int tid = threadIdx.x;
  int lane = tid & 63, w = tid >> 6;
  int wr = w >> 1, wc = w & 1;
  int lg = lane >> 4, lq = lane & 15;
  int srow = lane >> 2, scol = (lane & 3) * 8;

  const u16* aS0; const u16* aS1 = nullptr;
  if constexpr (TM == 128) {
    aS0 = &A[(size_t)(m0 + w * 32 +      srow) * K + scol];
    aS1 = &A[(size_t)(m0 + w * 32 + 16 + srow) * K + scol];
  } else {
    aS0 = &A[(size_t)(m0 + w * 16 + srow) * K + scol];
  }
  const u16* bS0 = &Bt[(size_t)(n0 + w * 32 +      srow) * K + scol];
  const u16* bS1 = &Bt[(size_t)(n0 + w * 32 + 16 + srow) * K + scol];

  auto stage = [&](int buf, int k0) {
    if constexpr (TM == 128) {
      gload_lds16(aS0 + k0, &As[buf][w * 32][0]);
      gload_lds16(aS1 + k0, &As[buf][w * 32 + 16][0]);
    } else {
      gload_lds16(aS0 + k0, &As[buf][w * 16][0]);
    }
    gload_lds16(bS0 + k0, &Bs[buf][w * 32][0]);
    gload_lds16(bS1 + k0, &Bs[buf][w * 32 + 16][0]);
  };

  f32x4 acc[MF][4] = {};

  stage(0, 0);
  __syncthreads();               // vmcnt(0) drain: buf0 staged
  int cur = 0;
  for (int k0 = 0; k0 < K; k0 += 32) {
    if (k0 + 32 < K) stage(cur ^ 1, k0 + 32);   // prefetch next tile (other buffer)
    short8 af[MF], bf[4];
#pragma unroll
    for (int m = 0; m < MF; m++) af[m] = *(const short8*)&As[cur][wr * (TM / 2) + m * 16 + lq][lg * 8];
#pragma unroll
    for (int n = 0; n < 4; n++) bf[n] = *(const short8*)&Bs[cur][wc * 64 + n * 16 + lq][lg * 8];
#pragma unroll
    for (int m = 0; m < MF; m++)
#pragma unroll
      for (int n = 0; n < 4; n++)
        acc[m][n] = __builtin_amdgcn_mfma_f32_16x16x32_bf16(af[m], bf[n], acc[m][n], 0, 0, 0);
    __syncthreads();             // prefetch complete + all reads of cur done
    cur ^= 1;
  }

#pragma unroll
  for (int m = 0; m < MF; m++)
#pragma unroll
    for (int n = 0; n < 4; n++) {
      int row = m0 + wr * (TM / 2) + m * 16 + lg * 4;
      int col = n0 + wc * 64 + n * 16 + lq;
      float bv = BIAS ? bias[col] : 0.f;
#pragma unroll
      for (int r = 0; r < 4; r++) {
        float v = acc[m][n][r];
        if (BIAS) v += bv;
        if (RES)  v += res[(size_t)(row + r) * N + col];
        if (RELU) v = fmaxf(v, 0.f);
        if (OF32) outf[(size_t)(row + r) * N + col] = v;
        if (OBF)  outb[(size_t)(row + r) * N + col] = f2bf(v);
      }
    }
}

// ---------------- causal flash attention: 4 waves / 64-query block ----------------
// qkv: bf16 [M_][3072], cols: Q = h*64+d, K = 1024+h*64+d (V unused here).
// Vt: bf16 [E_][M_].  K,V tiles (KVBLK=64) staged in LDS once per block.
__global__ __launch_bounds__(256) void attn_kernel(const u16* __restrict__ qkv,
                                                   const u16* __restrict__ Vt,
                                                   u16* __restrict__ attn) {
  __shared__ __attribute__((aligned(16))) u16 Ks[64][72];
  __shared__ __attribute__((aligned(16))) u16 Vs[64][72];   // rows=d, cols=s
  __shared__ u16 Ps[4][64][20];                             // per-wave P^T [s][q]
  int bid = blockIdx.x;
  int j  = bid & 31;
  int qt = (j & 1) ? (31 - (j >> 1)) : (j >> 1);  // heavy/light pairing
  int h  = (bid >> 5) & 15;
  int b  = bid >> 9;
  int tid = threadIdx.x;
  int lane = tid & 63, w = tid >> 6;
  int lg = lane >> 4, lq = lane & 15;
  int q_first = qt * 64 + w * 16;
  int q_abs = q_first + lq;

  const size_t rowQ = (size_t)(b * T_ + q_first + lq) * NQKV_ + h * 64;
  short8 qf0 = *(const short8*)&qkv[rowQ + lg * 8];
  short8 qf1 = *(const short8*)&qkv[rowQ + 32 + lg * 8];

  const u16* Kbase  = qkv + (size_t)(b * T_) * NQKV_ + 1024 + h * 64;
  const u16* Vtbase = Vt + (size_t)(h * 64) * M_ + b * T_;

  // staging decomposition: 512 uint4 per tile per matrix; 2 per thread
  int u0 = tid, u1 = tid + 256;
  int r0s = u0 >> 3, c0s = (u0 & 7) * 8;
  int r1s = u1 >> 3, c1s = (u1 & 7) * 8;

  f32x4 o[4] = {};
  float m_run = -__builtin_inff(), l_run = 0.f;
  const float scale = 0.03125f;  // E_^-0.5 (faithful: reference scales by C**-0.5)
  const int s_end = qt * 64 + 63;

  for (int s0 = 0; s0 <= s_end; s0 += 64) {
    __syncthreads();
    *(uint4*)&Ks[r0s][c0s] = *(const uint4*)&Kbase[(size_t)(s0 + r0s) * NQKV_ + c0s];
    *(uint4*)&Ks[r1s][c1s] = *(const uint4*)&Kbase[(size_t)(s0 + r1s) * NQKV_ + c1s];
    *(uint4*)&Vs[r0s][c0s] = *(const uint4*)&Vtbase[(size_t)r0s * M_ + s0 + c0s];
    *(uint4*)&Vs[r1s][c1s] = *(const uint4*)&Vtbase[(size_t)r1s * M_ + s0 + c1s];
    __syncthreads();
    if (s0 > q_first + 15) continue;   // tile fully masked for this wave (uniform)

    // --- S^T = K @ Q^T over 4 sub-tiles of 16 keys ---
    f32x4 st[4];
#pragma unroll
    for (int t2 = 0; t2 < 4; t2++) {
      short8 kf0 = *(const short8*)&Ks[t2 * 16 + lq][lg * 8];
      short8 kf1 = *(const short8*)&Ks[t2 * 16 + lq][32 + lg * 8];
      f32x4 c = {};
      c = __builtin_amdgcn_mfma_f32_16x16x32_bf16(kf0, qf0, c, 0, 0, 0);
      c = __builtin_amdgcn_mfma_f32_16x16x32_bf16(kf1, qf1, c, 0, 0, 0);
      st[t2] = c;
    }
    // --- scale + causal mask + tile max ---
    float tmax = -__builtin_inff();
#pragma unroll
    for (int t2 = 0; t2 < 4; t2++)
#pragma unroll
      for (int r = 0; r < 4; r++) {
        int s_abs = s0 + t2 * 16 + lg * 4 + r;
        float v = st[t2][r] * scale;
        v = (s_abs > q_abs) ? -__builtin_inff() : v;
        st[t2][r] = v;
        tmax = fmaxf(tmax, v);
      }
    tmax = fmaxf(tmax, __shfl_xor(tmax, 16));
    tmax = fmaxf(tmax, __shfl_xor(tmax, 32));
    float newm = fmaxf(m_run, tmax);
    float fac = __expf(m_run - newm);
    m_run = newm;
    float psum = 0.f;
#pragma unroll
    for (int t2 = 0; t2 < 4; t2++)
#pragma unroll
      for (int r = 0; r < 4; r++) {
        float p = __expf(st[t2][r] - newm);
        st[t2][r] = p;
        psum += p;
      }
    psum += __shfl_xor(psum, 16);
    psum += __shfl_xor(psum, 32);
    l_run = l_run * fac + psum;
#pragma unroll
    for (int c = 0; c < 4; c++) o[c] *= fac;

    // --- P (C-layout) -> per-wave LDS -> B-fragment layout ---
#pragma unroll
    for (int t2 = 0; t2 < 4; t2++)
#pragma unroll
      for (int r = 0; r < 4; r++)
        Ps[w][t2 * 16 + lg * 4 + r][lq] = f2bf(st[t2][r]);

    // --- O^T += V^T @ P^T  (2 k-chunks of 32 keys) ---
#pragma unroll
    for (int ks = 0; ks < 2; ks++) {
      short8 pf;
#pragma unroll
      for (int v = 0; v < 8; v++) pf[v] = (short)Ps[w][ks * 32 + lg * 8 + v][lq];
#pragma unroll
      for (int c = 0; c < 4; c++) {
        short8 vf = *(const short8*)&Vs[c * 16 + lq][ks * 32 + lg * 8];
        o[c] = __builtin_amdgcn_mfma_f32_16x16x32_bf16(vf, pf, o[c], 0, 0, 0);
      }
    }
  }

  float inv = 1.f / l_run;
  const size_t orow = (size_t)(b * T_ + q_first + lq) * E_ + h * 64;
#pragma unroll
  for (int c = 0; c < 4; c++) {
    uint2 r;
    r.x = (unsigned)f2bf(o[c][0] * inv) | ((unsigned)f2bf(o[c][1] * inv) << 16);
    r.y = (unsigned)f2bf(o[c][2] * inv) | ((unsigned)f2bf(o[c][3] * inv) << 16);
    *(uint2*)&attn[orow + c * 16 + lg * 4] = r;
  }
}

// ---------------- launch ----------------
extern "C" void kernel_launch(void* const* d_in, const int* in_sizes, int n_in,
                              void* d_out, int out_size, void* d_ws, size_t ws_size,
                              hipStream_t stream) {
  const float* x  = (const float*)d_in[0];
  const float* Wq = (const float*)d_in[1];
  const float* Wk = (const float*)d_in[2];
  const float* Wv = (const float*)d_in[3];
  const float* Wo = (const float*)d_in[4];
  const float* bo = (const float*)d_in[5];
  const float* W1 = (const float*)d_in[6];
  const float* b1 = (const float*)d_in[7];
  const float* W2 = (const float*)d_in[8];
  const float* b2 = (const float*)d_in[9];
  float* out = (float*)d_out;

  const size_t MB = 1048576;
  char* ws = (char*)d_ws;
  u16* xb    = (u16*)(ws + 0);          // 8MB   (x1b aliases after QKV GEMM)
  u16* WqkvT = (u16*)(ws + 8 * MB);     // 6MB   [3072][1024]
  u16* WoT   = (u16*)(ws + 14 * MB);    // 2MB
  u16* W1T   = (u16*)(ws + 16 * MB);    // 8MB
  u16* W2T   = (u16*)(ws + 24 * MB);    // 8MB
  u16* qkv   = (u16*)(ws + 32 * MB);    // 24MB  [4096][3072] (dead after attn)
  u16* attn  = (u16*)(ws + 56 * MB);    // 8MB   (dead after proj)
  float* x1  = (float*)(ws + 64 * MB);  // 16MB  (written by proj, after Vt dead)
  u16* Vtb   = (u16*)(ws + 64 * MB);    // 8MB   overlaps x1 (dead before x1 written)
  u16* x1b   = (u16*)(ws + 0);          // alias xb
  u16* hbuf  = (u16*)(ws + 32 * MB);    // 32MB  alias qkv+attn (dead after proj)

  // prep: cast + weight transposes to [N][K] bf16
  cast_bf16_kernel<<<(M_ * E_ / 4 + 255) / 256, 256, 0, stream>>>(x, xb, M_ * E_ / 4);
  transpose_cast_kernel<<<dim3(2, 32, 16),  256, 0, stream>>>(Wq, WqkvT,                E_, D_, E_);
  transpose_cast_kernel<<<dim3(2, 32, 16),  256, 0, stream>>>(Wk, WqkvT + 1024 * 1024,  E_, D_, E_);
  transpose_cast_kernel<<<dim3(2, 32, 16),  256, 0, stream>>>(Wv, WqkvT + 2048 * 1024,  E_, D_, E_);
  transpose_cast_kernel<<<dim3(32, 32, 1),  256, 0, stream>>>(Wo, WoT, E_, E_, E_);
  transpose_cast_kernel<<<dim3(128, 32, 1), 256, 0, stream>>>(W1, W1T, E_, DF_, E_);
  transpose_cast_kernel<<<dim3(32, 128, 1), 256, 0, stream>>>(W2, W2T, DF_, E_, DF_);

  // fused QKV GEMM: qkv[M][3072]
  gemm_bt<128,false,false,false,false,true><<<dim3(NQKV_ / 128, M_ / 128), 256, 0, stream>>>(
      xb, WqkvT, M_, NQKV_, E_, nullptr, nullptr, nullptr, qkv);

  // V -> V^T  (qkv cols 2048..3071 -> Vt[E][M])
  transpose_u16_kernel<<<dim3(E_ / 64, M_ / 64), 256, 0, stream>>>(qkv + 2048, Vtb, M_, E_, NQKV_);

  attn_kernel<<<B_ * H_ * (T_ / 64), 256, 0, stream>>>(qkv, Vtb, attn);

  // x1 = x + attn @ Wo + bo   (fp32 + bf16 mirror); TM=64 -> 512 blocks
  gemm_bt<64,true,false,true,true,true><<<dim3(E_ / 128, M_ / 64), 256, 0, stream>>>(
      attn, WoT, M_, E_, E_, bo, x, x1, x1b);
  // h = relu(x1 @ W1 + b1)
  gemm_bt<128,true,true,false,false,true><<<dim3(DF_ / 128, M_ / 128), 256, 0, stream>>>(
      x1b, W1T, M_, DF_, E_, b1, nullptr, nullptr, hbuf);
  // out = x1 + h @ W2 + b2 ; TM=64 -> 512 blocks
  gemm_bt<64,true,false,true,true,false><<<dim3(E_ / 128, M_ / 64), 256, 0, stream>>>(
      hbuf, W2T, M_, E_, DF_, b2, x1, out, nullptr);
}

// Round 6
// 285.389 us; speedup vs baseline: 1.6073x; 1.0220x over previous
//
#include <hip/hip_runtime.h>

#define B_ 2
#define T_ 2048
#define E_ 1024
#define H_ 16
#define D_ 64
#define DF_ 4096
#define M_ (B_*T_)   // 4096 rows
#define NQKV_ 3072   // fused QKV output width

typedef unsigned short u16;
typedef __attribute__((ext_vector_type(8))) short short8;
typedef __attribute__((ext_vector_type(4))) float f32x4;
typedef __attribute__((ext_vector_type(16))) float f32x16;

__device__ __forceinline__ u16 f2bf(float f) {
  unsigned u = __builtin_bit_cast(unsigned, f);
  u += 0x7FFFu + ((u >> 16) & 1u);   // RNE
  return (u16)(u >> 16);
}
__device__ __forceinline__ unsigned pack2bf(float a, float b) {
  return (unsigned)f2bf(a) | ((unsigned)f2bf(b) << 16);
}

// async global->LDS DMA, 16B per lane; LDS dest = wave-uniform base + lane*16
__device__ __forceinline__ void gload_lds16(const u16* g, u16* l) {
  __builtin_amdgcn_global_load_lds((const __attribute__((address_space(1))) void*)g,
                                   (__attribute__((address_space(3))) void*)l, 16, 0, 0);
}

// ---------------- cast fp32 -> bf16 (vectorized x4) ----------------
__global__ __launch_bounds__(256) void cast_bf16_kernel(const float* __restrict__ in,
                                                        u16* __restrict__ out, int n4) {
  int i = blockIdx.x * 256 + threadIdx.x;
  if (i >= n4) return;
  float4 v = ((const float4*)in)[i];
  uint2 r;
  r.x = (unsigned)f2bf(v.x) | ((unsigned)f2bf(v.y) << 16);
  r.y = (unsigned)f2bf(v.z) | ((unsigned)f2bf(v.w) << 16);
  ((uint2*)out)[i] = r;
}

// ---------------- tiled transpose + cast: in[z][r][c] (f32) -> out[(z*C+c)*outld + r] (bf16)
__global__ __launch_bounds__(256) void transpose_cast_kernel(const float* __restrict__ in,
                                                             u16* __restrict__ out,
                                                             int R, int C, int outld) {
  __shared__ float tile[32][33];
  int z = blockIdx.z;
  int c0 = blockIdx.x * 32, r0 = blockIdx.y * 32;
  int tx = threadIdx.x & 31, ty = threadIdx.x >> 5;
  const float* ip = in + (size_t)z * R * C;
#pragma unroll
  for (int i = 0; i < 32; i += 8)
    tile[ty + i][tx] = ip[(size_t)(r0 + ty + i) * C + (c0 + tx)];
  __syncthreads();
#pragma unroll
  for (int i = 0; i < 32; i += 8)
    out[(size_t)(z * C + c0 + ty + i) * outld + (r0 + tx)] = f2bf(tile[tx][ty + i]);
}

// ---------------- u16 transpose: in[R][C] (row stride ldin) -> out[C][R], 64x64 tiles ----
__global__ __launch_bounds__(256) void transpose_u16_kernel(const u16* __restrict__ in,
                                                            u16* __restrict__ out,
                                                            int R, int C, int ldin) {
  __shared__ __attribute__((aligned(16))) u16 tile[64][72];
  int c0 = blockIdx.x * 64, r0 = blockIdx.y * 64;
  int t = threadIdx.x;
  int tr = t >> 4, tc = (t & 15) * 4;
#pragma unroll
  for (int i = 0; i < 4; i++)
    *(uint2*)&tile[tr + i * 16][tc] = *(const uint2*)&in[(size_t)(r0 + tr + i * 16) * ldin + c0 + tc];
  __syncthreads();
  int rr = (t & 15) * 4, cc0 = t >> 4;
#pragma unroll
  for (int i = 0; i < 4; i++) {
    int cc = cc0 + i * 16;
    u16 a = tile[rr][cc], b = tile[rr + 1][cc], c = tile[rr + 2][cc], d = tile[rr + 3][cc];
    uint2 v;
    v.x = (unsigned)a | ((unsigned)b << 16);
    v.y = (unsigned)c | ((unsigned)d << 16);
    *(uint2*)&out[(size_t)(c0 + cc) * R + r0 + rr] = v;
  }
}

// ---------------- bf16 MFMA GEMM: C[M,N] = A[M,K] @ Bt[N,K]^T ----------------
// TM x 128 tile, 4 waves (2x2), BK=32, DOUBLE-BUFFERED linear LDS staged via
// global_load_lds w=16; 2-phase pipeline: prefetch k+1 before computing k,
// ONE barrier per K-step (syncthreads drains vmcnt -> prefetch visible).
template<int TM, bool BIAS, bool RELU, bool RES, bool OF32, bool OBF>
__global__ __launch_bounds__(256, 2) void gemm_bt(const u16* __restrict__ A,
                                                  const u16* __restrict__ Bt,
                                                  int M, int N, int K,
                                                  const float* __restrict__ bias,
                                                  const float* __restrict__ res,
                                                  float* __restrict__ outf,
                                                  u16* __restrict__ outb) {
  constexpr int MF = TM / 32;   // m-fragments per wave
  __shared__ __attribute__((aligned(16))) u16 As[2][TM][32];
  __shared__ __attribute__((aligned(16))) u16 Bs[2][128][32];
  int m0 = blockIdx.y * TM, n0 = blockIdx.x * 128;
  int tid = threadIdx.x;
  int lane = tid & 63, w = tid >> 6;
  int wr = w >> 1, wc = w & 1;
  int lg = lane >> 4, lq = lane & 15;
  int srow = lane >> 2, scol = (lane & 3) * 8;

  const u16* aS0; const u16* aS1 = nullptr;
  if constexpr (TM == 128) {
    aS0 = &A[(size_t)(m0 + w * 32 +      srow) * K + scol];
    aS1 = &A[(size_t)(m0 + w * 32 + 16 + srow) * K + scol];
  } else {
    aS0 = &A[(size_t)(m0 + w * 16 + srow) * K + scol];
  }
  const u16* bS0 = &Bt[(size_t)(n0 + w * 32 +      srow) * K + scol];
  const u16* bS1 = &Bt[(size_t)(n0 + w * 32 + 16 + srow) * K + scol];

  auto stage = [&](int buf, int k0) {
    if constexpr (TM == 128) {
      gload_lds16(aS0 + k0, &As[buf][w * 32][0]);
      gload_lds16(aS1 + k0, &As[buf][w * 32 + 16][0]);
    } else {
      gload_lds16(aS0 + k0, &As[buf][w * 16][0]);
    }
    gload_lds16(bS0 + k0, &Bs[buf][w * 32][0]);
    gload_lds16(bS1 + k0, &Bs[buf][w * 32 + 16][0]);
  };

  f32x4 acc[MF][4] = {};

  stage(0, 0);
  __syncthreads();               // vmcnt(0) drain: buf0 staged
  int cur = 0;
  for (int k0 = 0; k0 < K; k0 += 32) {
    if (k0 + 32 < K) stage(cur ^ 1, k0 + 32);   // prefetch next tile (other buffer)
    short8 af[MF], bf[4];
#pragma unroll
    for (int m = 0; m < MF; m++) af[m] = *(const short8*)&As[cur][wr * (TM / 2) + m * 16 + lq][lg * 8];
#pragma unroll
    for (int n = 0; n < 4; n++) bf[n] = *(const short8*)&Bs[cur][wc * 64 + n * 16 + lq][lg * 8];
#pragma unroll
    for (int m = 0; m < MF; m++)
#pragma unroll
      for (int n = 0; n < 4; n++)
        acc[m][n] = __builtin_amdgcn_mfma_f32_16x16x32_bf16(af[m], bf[n], acc[m][n], 0, 0, 0);
    __syncthreads();             // prefetch complete + all reads of cur done
    cur ^= 1;
  }

#pragma unroll
  for (int m = 0; m < MF; m++)
#pragma unroll
    for (int n = 0; n < 4; n++) {
      int row = m0 + wr * (TM / 2) + m * 16 + lg * 4;
      int col = n0 + wc * 64 + n * 16 + lq;
      float bv = BIAS ? bias[col] : 0.f;
#pragma unroll
      for (int r = 0; r < 4; r++) {
        float v = acc[m][n][r];
        if (BIAS) v += bv;
        if (RES)  v += res[(size_t)(row + r) * N + col];
        if (RELU) v = fmaxf(v, 0.f);
        if (OF32) outf[(size_t)(row + r) * N + col] = v;
        if (OBF)  outb[(size_t)(row + r) * N + col] = f2bf(v);
      }
    }
}

// ---------------- causal flash attention v3: 4 waves x 32 queries, 32x32 MFMA ----------
// qkv: bf16 [M_][3072] (Q at col h*64+d, K at 1024+h*64+d). Vt: bf16 [E_][M_].
// Swapped S^T = K@Q^T via mfma_32x32x16; softmax per query = local 16-reg reduce +
// one shfl_xor(32); P kept IN REGISTERS (pack bf16 pairs + half-swap via shfl_xor).
// K/V staged in linear LDS tiles with XOR swizzle byte^=((row&7)<<4) -> all b128
// fragment reads and uint4 staging writes hit the 8-words/bank floor (conflict-free).
__global__ __launch_bounds__(256) void attn_kernel(const u16* __restrict__ qkv,
                                                   const u16* __restrict__ Vt,
                                                   u16* __restrict__ attn) {
  __shared__ __attribute__((aligned(16))) u16 Ks[64 * 64];   // [key][d], swizzled
  __shared__ __attribute__((aligned(16))) u16 Vs[64 * 64];   // [d][s],  swizzled
  int bid = blockIdx.x;
  int j  = bid & 15;
  int qt = (j & 1) ? (15 - (j >> 1)) : (j >> 1);  // heavy/light pairing (16 q-tiles)
  int h  = (bid >> 4) & 15;
  int b  = bid >> 8;
  int tid = threadIdx.x;
  int lane = tid & 63, w = tid >> 6;
  int l31 = lane & 31, hh = lane >> 5;
  int q0w = qt * 128 + w * 32;
  int q_abs = q0w + l31;

  // Q B-fragments: col=q (l31), k = ks*16 + hh*8 + j
  short8 qf[4];
  const u16* Qrow = qkv + (size_t)(b * T_ + q_abs) * NQKV_ + h * 64;
#pragma unroll
  for (int ks = 0; ks < 4; ks++) qf[ks] = *(const short8*)&Qrow[ks * 16 + hh * 8];

  const u16* Kbase  = qkv + (size_t)(b * T_) * NQKV_ + 1024 + h * 64;
  const u16* Vtbase = Vt + (size_t)(h * 64) * M_ + b * T_;

  // staging: 512 uint4 per matrix / 256 threads = 2 each
  int r0s = tid >> 3, c0s = tid & 7;           // rows 0..31
  int r1s = r0s + 32;                          // rows 32..63
  unsigned kd0 = (unsigned)((r0s * 128 + c0s * 16) ^ ((r0s & 7) << 4));
  unsigned kd1 = (unsigned)((r1s * 128 + c0s * 16) ^ ((r1s & 7) << 4));

  f32x16 o[2] = {};
  float m_run = -__builtin_inff(), l_run = 0.f;
  const float scale = 0.03125f;  // E_^-0.5 (faithful: reference scales by C**-0.5)
  const int s_stop = qt * 128 + 128;

  for (int s0 = 0; s0 < s_stop; s0 += 64) {
    __syncthreads();
    *(uint4*)((char*)Ks + kd0) = *(const uint4*)&Kbase[(size_t)(s0 + r0s) * NQKV_ + c0s * 8];
    *(uint4*)((char*)Ks + kd1) = *(const uint4*)&Kbase[(size_t)(s0 + r1s) * NQKV_ + c0s * 8];
    *(uint4*)((char*)Vs + kd0) = *(const uint4*)&Vtbase[(size_t)r0s * M_ + s0 + c0s * 8];
    *(uint4*)((char*)Vs + kd1) = *(const uint4*)&Vtbase[(size_t)r1s * M_ + s0 + c0s * 8];
    __syncthreads();
    if (s0 > q0w + 31) continue;   // tile fully masked for this wave (wave-uniform)

    // --- S^T = K @ Q^T : 2 key-chunks of 32, accumulate over 4 d-slices ---
    f32x16 st[2];
#pragma unroll
    for (int c = 0; c < 2; c++) {
      f32x16 acc = {};
      int key = c * 32 + l31;
#pragma unroll
      for (int ks = 0; ks < 4; ks++) {
        unsigned off = (unsigned)((key * 128 + ks * 32 + hh * 16) ^ ((key & 7) << 4));
        short8 kf = *(const short8*)((const char*)Ks + off);
        acc = __builtin_amdgcn_mfma_f32_32x32x16_bf16(kf, qf[ks], acc, 0, 0, 0);
      }
      st[c] = acc;
    }

    // --- scale + causal mask + tile max (key = s0 + c*32 + (r&3)+8*(r>>2)+4*hh) ---
    float tmax = -__builtin_inff();
    bool need_mask = (s0 + 63 > q0w);
#pragma unroll
    for (int c = 0; c < 2; c++)
#pragma unroll
      for (int r = 0; r < 16; r++) {
        int key = s0 + c * 32 + (r & 3) + 8 * (r >> 2) + 4 * hh;
        float v = st[c][r] * scale;
        if (need_mask) v = (key > q_abs) ? -__builtin_inff() : v;
        st[c][r] = v;
        tmax = fmaxf(tmax, v);
      }
    tmax = fmaxf(tmax, __shfl_xor(tmax, 32));
    float newm = fmaxf(m_run, tmax);
    float fac = __expf(m_run - newm);
    m_run = newm;
    float psum = 0.f;
#pragma unroll
    for (int c = 0; c < 2; c++)
#pragma unroll
      for (int r = 0; r < 16; r++) {
        float p = __expf(st[c][r] - newm);
        st[c][r] = p;
        psum += p;
      }
    psum += __shfl_xor(psum, 32);
    l_run = l_run * fac + psum;
    o[0] *= fac;
    o[1] *= fac;

    // --- pack P to bf16 words: wds[c][2a+b2] = pack(p[4a+2b2], p[4a+2b2+1]) ---
    unsigned wds[2][8];
#pragma unroll
    for (int c = 0; c < 2; c++)
#pragma unroll
      for (int i = 0; i < 8; i++)
        wds[c][i] = pack2bf(st[c][2 * i], st[c][2 * i + 1]);

    // --- O^T += V^T @ P^T : 4 key-slices of 16, B-frag built in-register ---
#pragma unroll
    for (int ks16 = 0; ks16 < 4; ks16++) {
      int c = ks16 >> 1, e = ks16 & 1;
      // receiver needs quad a = 2e + hh from BOTH halves; sender ships the quad
      // the partner needs (hh=0 ships quad 2e+1, hh=1 ships quad 2e)
      unsigned send0 = hh ? wds[c][4 * e]     : wds[c][4 * e + 2];
      unsigned send1 = hh ? wds[c][4 * e + 1] : wds[c][4 * e + 3];
      unsigned recv0 = (unsigned)__shfl_xor((int)send0, 32);
      unsigned recv1 = (unsigned)__shfl_xor((int)send1, 32);
      uint4 fw;
      fw.x = hh ? recv0 : wds[c][4 * e];
      fw.y = hh ? recv1 : wds[c][4 * e + 1];
      fw.z = hh ? wds[c][4 * e + 2] : recv0;
      fw.w = hh ? wds[c][4 * e + 3] : recv1;
      short8 pf = __builtin_bit_cast(short8, fw);
#pragma unroll
      for (int dc = 0; dc < 2; dc++) {
        int d = dc * 32 + l31;
        unsigned off = (unsigned)((d * 128 + ks16 * 32 + hh * 16) ^ ((d & 7) << 4));
        short8 vf = *(const short8*)((const char*)Vs + off);
        o[dc] = __builtin_amdgcn_mfma_f32_32x32x16_bf16(vf, pf, o[dc], 0, 0, 0);
      }
    }
  }

  // --- epilogue: O^T col=q (l31), row d = dc*32 + 8a + 4hh + (r&3); store uint2 ---
  float inv = 1.f / l_run;
  const size_t orow = (size_t)(b * T_ + q_abs) * E_ + h * 64;
#pragma unroll
  for (int dc = 0; dc < 2; dc++)
#pragma unroll
    for (int a = 0; a < 4; a++) {
      uint2 r;
      r.x = pack2bf(o[dc][4 * a] * inv, o[dc][4 * a + 1] * inv);
      r.y = pack2bf(o[dc][4 * a + 2] * inv, o[dc][4 * a + 3] * inv);
      *(uint2*)&attn[orow + dc * 32 + 8 * a + 4 * hh] = r;
    }
}

// ---------------- launch ----------------
extern "C" void kernel_launch(void* const* d_in, const int* in_sizes, int n_in,
                              void* d_out, int out_size, void* d_ws, size_t ws_size,
                              hipStream_t stream) {
  const float* x  = (const float*)d_in[0];
  const float* Wq = (const float*)d_in[1];
  const float* Wk = (const float*)d_in[2];
  const float* Wv = (const float*)d_in[3];
  const float* Wo = (const float*)d_in[4];
  const float* bo = (const float*)d_in[5];
  const float* W1 = (const float*)d_in[6];
  const float* b1 = (const float*)d_in[7];
  const float* W2 = (const float*)d_in[8];
  const float* b2 = (const float*)d_in[9];
  float* out = (float*)d_out;

  const size_t MB = 1048576;
  char* ws = (char*)d_ws;
  u16* xb    = (u16*)(ws + 0);          // 8MB   (x1b aliases after QKV GEMM)
  u16* WqkvT = (u16*)(ws + 8 * MB);     // 6MB   [3072][1024]
  u16* WoT   = (u16*)(ws + 14 * MB);    // 2MB
  u16* W1T   = (u16*)(ws + 16 * MB);    // 8MB
  u16* W2T   = (u16*)(ws + 24 * MB);    // 8MB
  u16* qkv   = (u16*)(ws + 32 * MB);    // 24MB  [4096][3072] (dead after attn)
  u16* attn  = (u16*)(ws + 56 * MB);    // 8MB   (dead after proj)
  float* x1  = (float*)(ws + 64 * MB);  // 16MB  (written by proj, after Vt dead)
  u16* Vtb   = (u16*)(ws + 64 * MB);    // 8MB   overlaps x1 (dead before x1 written)
  u16* x1b   = (u16*)(ws + 0);          // alias xb
  u16* hbuf  = (u16*)(ws + 32 * MB);    // 32MB  alias qkv+attn (dead after proj)

  // prep: cast + weight transposes to [N][K] bf16
  cast_bf16_kernel<<<(M_ * E_ / 4 + 255) / 256, 256, 0, stream>>>(x, xb, M_ * E_ / 4);
  transpose_cast_kernel<<<dim3(2, 32, 16),  256, 0, stream>>>(Wq, WqkvT,                E_, D_, E_);
  transpose_cast_kernel<<<dim3(2, 32, 16),  256, 0, stream>>>(Wk, WqkvT + 1024 * 1024,  E_, D_, E_);
  transpose_cast_kernel<<<dim3(2, 32, 16),  256, 0, stream>>>(Wv, WqkvT + 2048 * 1024,  E_, D_, E_);
  transpose_cast_kernel<<<dim3(32, 32, 1),  256, 0, stream>>>(Wo, WoT, E_, E_, E_);
  transpose_cast_kernel<<<dim3(128, 32, 1), 256, 0, stream>>>(W1, W1T, E_, DF_, E_);
  transpose_cast_kernel<<<dim3(32, 128, 1), 256, 0, stream>>>(W2, W2T, DF_, E_, DF_);

  // fused QKV GEMM: qkv[M][3072]
  gemm_bt<128,false,false,false,false,true><<<dim3(NQKV_ / 128, M_ / 128), 256, 0, stream>>>(
      xb, WqkvT, M_, NQKV_, E_, nullptr, nullptr, nullptr, qkv);

  // V -> V^T  (qkv cols 2048..3071 -> Vt[E][M])
  transpose_u16_kernel<<<dim3(E_ / 64, M_ / 64), 256, 0, stream>>>(qkv + 2048, Vtb, M_, E_, NQKV_);

  attn_kernel<<<B_ * H_ * (T_ / 128), 256, 0, stream>>>(qkv, Vtb, attn);

  // x1 = x + attn @ Wo + bo   (fp32 + bf16 mirror); TM=64 -> 512 blocks
  gemm_bt<64,true,false,true,true,true><<<dim3(E_ / 128, M_ / 64), 256, 0, stream>>>(
      attn, WoT, M_, E_, E_, bo, x, x1, x1b);
  // h = relu(x1 @ W1 + b1)
  gemm_bt<128,true,true,false,false,true><<<dim3(DF_ / 128, M_ / 128), 256, 0, stream>>>(
      x1b, W1T, M_, DF_, E_, b1, nullptr, nullptr, hbuf);
  // out = x1 + h @ W2 + b2 ; TM=64 -> 512 blocks
  gemm_bt<64,true,false,true,true,false><<<dim3(E_ / 128, M_ / 64), 256, 0, stream>>>(
      hbuf, W2T, M_, E_, DF_, b2, x1, out, nullptr);
}

// Round 7
// 254.184 us; speedup vs baseline: 1.8046x; 1.1228x over previous
//
#include <hip/hip_runtime.h>

#define B_ 2
#define T_ 2048
#define E_ 1024
#define H_ 16
#define D_ 64
#define DF_ 4096
#define M_ (B_*T_)   // 4096 rows
#define NQKV_ 3072   // fused QKV output width

typedef unsigned short u16;
typedef __attribute__((ext_vector_type(8))) short short8;
typedef __attribute__((ext_vector_type(4))) float f32x4;
typedef __attribute__((ext_vector_type(16))) float f32x16;

__device__ __forceinline__ u16 f2bf(float f) {
  unsigned u = __builtin_bit_cast(unsigned, f);
  u += 0x7FFFu + ((u >> 16) & 1u);   // RNE
  return (u16)(u >> 16);
}
__device__ __forceinline__ unsigned pack2bf(float a, float b) {
  return (unsigned)f2bf(a) | ((unsigned)f2bf(b) << 16);
}

// async global->LDS DMA, 16B per lane; LDS dest = wave-uniform base + lane*16
__device__ __forceinline__ void gload_lds16(const u16* g, u16* l) {
  __builtin_amdgcn_global_load_lds((const __attribute__((address_space(1))) void*)g,
                                   (__attribute__((address_space(3))) void*)l, 16, 0, 0);
}

// ---------------- cast fp32 -> bf16 (vectorized x4) ----------------
__global__ __launch_bounds__(256) void cast_bf16_kernel(const float* __restrict__ in,
                                                        u16* __restrict__ out, int n4) {
  int i = blockIdx.x * 256 + threadIdx.x;
  if (i >= n4) return;
  float4 v = ((const float4*)in)[i];
  uint2 r;
  r.x = (unsigned)f2bf(v.x) | ((unsigned)f2bf(v.y) << 16);
  r.y = (unsigned)f2bf(v.z) | ((unsigned)f2bf(v.w) << 16);
  ((uint2*)out)[i] = r;
}

// ---------------- tiled transpose + cast: in[z][r][c] (f32) -> out[(z*C+c)*outld + r] (bf16)
__global__ __launch_bounds__(256) void transpose_cast_kernel(const float* __restrict__ in,
                                                             u16* __restrict__ out,
                                                             int R, int C, int outld) {
  __shared__ float tile[32][33];
  int z = blockIdx.z;
  int c0 = blockIdx.x * 32, r0 = blockIdx.y * 32;
  int tx = threadIdx.x & 31, ty = threadIdx.x >> 5;
  const float* ip = in + (size_t)z * R * C;
#pragma unroll
  for (int i = 0; i < 32; i += 8)
    tile[ty + i][tx] = ip[(size_t)(r0 + ty + i) * C + (c0 + tx)];
  __syncthreads();
#pragma unroll
  for (int i = 0; i < 32; i += 8)
    out[(size_t)(z * C + c0 + ty + i) * outld + (r0 + tx)] = f2bf(tile[tx][ty + i]);
}

// ---------------- u16 transpose: in[R][C] (row stride ldin) -> out[C][R], 64x64 tiles ----
__global__ __launch_bounds__(256) void transpose_u16_kernel(const u16* __restrict__ in,
                                                            u16* __restrict__ out,
                                                            int R, int C, int ldin) {
  __shared__ __attribute__((aligned(16))) u16 tile[64][72];
  int c0 = blockIdx.x * 64, r0 = blockIdx.y * 64;
  int t = threadIdx.x;
  int tr = t >> 4, tc = (t & 15) * 4;
#pragma unroll
  for (int i = 0; i < 4; i++)
    *(uint2*)&tile[tr + i * 16][tc] = *(const uint2*)&in[(size_t)(r0 + tr + i * 16) * ldin + c0 + tc];
  __syncthreads();
  int rr = (t & 15) * 4, cc0 = t >> 4;
#pragma unroll
  for (int i = 0; i < 4; i++) {
    int cc = cc0 + i * 16;
    u16 a = tile[rr][cc], b = tile[rr + 1][cc], c = tile[rr + 2][cc], d = tile[rr + 3][cc];
    uint2 v;
    v.x = (unsigned)a | ((unsigned)b << 16);
    v.y = (unsigned)c | ((unsigned)d << 16);
    *(uint2*)&out[(size_t)(c0 + cc) * R + r0 + rr] = v;
  }
}

// ---------------- bf16 MFMA GEMM: C[M,N] = A[M,K] @ Bt[N,K]^T ----------------
// TM x 128 tile, 4 waves (2x2), BK=32, DOUBLE-BUFFERED linear LDS staged via
// global_load_lds w=16; 2-phase pipeline: prefetch k+1 before computing k,
// ONE barrier per K-step (syncthreads drains vmcnt -> prefetch visible).
template<int TM, bool BIAS, bool RELU, bool RES, bool OF32, bool OBF>
__global__ __launch_bounds__(256, 2) void gemm_bt(const u16* __restrict__ A,
                                                  const u16* __restrict__ Bt,
                                                  int M, int N, int K,
                                                  const float* __restrict__ bias,
                                                  const float* __restrict__ res,
                                                  float* __restrict__ outf,
                                                  u16* __restrict__ outb) {
  constexpr int MF = TM / 32;   // m-fragments per wave
  __shared__ __attribute__((aligned(16))) u16 As[2][TM][32];
  __shared__ __attribute__((aligned(16))) u16 Bs[2][128][32];
  int m0 = blockIdx.y * TM, n0 = blockIdx.x * 128;
  int tid = threadIdx.x;
  int lane = tid & 63, w = tid >> 6;
  int wr = w >> 1, wc = w & 1;
  int lg = lane >> 4, lq = lane & 15;
  int srow = lane >> 2, scol = (lane & 3) * 8;

  const u16* aS0; const u16* aS1 = nullptr;
  if constexpr (TM == 128) {
    aS0 = &A[(size_t)(m0 + w * 32 +      srow) * K + scol];
    aS1 = &A[(size_t)(m0 + w * 32 + 16 + srow) * K + scol];
  } else {
    aS0 = &A[(size_t)(m0 + w * 16 + srow) * K + scol];
  }
  const u16* bS0 = &Bt[(size_t)(n0 + w * 32 +      srow) * K + scol];
  const u16* bS1 = &Bt[(size_t)(n0 + w * 32 + 16 + srow) * K + scol];

  auto stage = [&](int buf, int k0) {
    if constexpr (TM == 128) {
      gload_lds16(aS0 + k0, &As[buf][w * 32][0]);
      gload_lds16(aS1 + k0, &As[buf][w * 32 + 16][0]);
    } else {
      gload_lds16(aS0 + k0, &As[buf][w * 16][0]);
    }
    gload_lds16(bS0 + k0, &Bs[buf][w * 32][0]);
    gload_lds16(bS1 + k0, &Bs[buf][w * 32 + 16][0]);
  };

  f32x4 acc[MF][4] = {};

  stage(0, 0);
  __syncthreads();               // vmcnt(0) drain: buf0 staged
  int cur = 0;
  for (int k0 = 0; k0 < K; k0 += 32) {
    if (k0 + 32 < K) stage(cur ^ 1, k0 + 32);   // prefetch next tile (other buffer)
    short8 af[MF], bf[4];
#pragma unroll
    for (int m = 0; m < MF; m++) af[m] = *(const short8*)&As[cur][wr * (TM / 2) + m * 16 + lq][lg * 8];
#pragma unroll
    for (int n = 0; n < 4; n++) bf[n] = *(const short8*)&Bs[cur][wc * 64 + n * 16 + lq][lg * 8];
#pragma unroll
    for (int m = 0; m < MF; m++)
#pragma unroll
      for (int n = 0; n < 4; n++)
        acc[m][n] = __builtin_amdgcn_mfma_f32_16x16x32_bf16(af[m], bf[n], acc[m][n], 0, 0, 0);
    __syncthreads();             // prefetch complete + all reads of cur done
    cur ^= 1;
  }

#pragma unroll
  for (int m = 0; m < MF; m++)
#pragma unroll
    for (int n = 0; n < 4; n++) {
      int row = m0 + wr * (TM / 2) + m * 16 + lg * 4;
      int col = n0 + wc * 64 + n * 16 + lq;
      float bv = BIAS ? bias[col] : 0.f;
#pragma unroll
      for (int r = 0; r < 4; r++) {
        float v = acc[m][n][r];
        if (BIAS) v += bv;
        if (RES)  v += res[(size_t)(row + r) * N + col];
        if (RELU) v = fmaxf(v, 0.f);
        if (OF32) outf[(size_t)(row + r) * N + col] = v;
        if (OBF)  outb[(size_t)(row + r) * N + col] = f2bf(v);
      }
    }
}

// ---------------- causal flash attention v4: 4 waves x 32 queries, 32x32 MFMA ----------
// qkv: bf16 [M_][3072] (Q at col h*64+d, K at 1024+h*64+d). Vt: bf16 [E_][M_].
// v4 changes: (1) CU-complementary bid remap: blocks c and c+256 land on the same CU
// and get qt j / 15-j -> every CU does exactly 34 staging-tile units;
// (2) T14 async-STAGE: next tile's global loads issued into regs right after the
// current ds_writes, written to LDS after the next barrier (latency hidden);
// (3) softmax: scale folded into exp via fmaf; mask pass only on diagonal tiles;
// T13 defer-max (skip o-rescale unless tmax - m_run > 256 raw = 8 p-exp units).
__global__ __launch_bounds__(256) void attn_kernel(const u16* __restrict__ qkv,
                                                   const u16* __restrict__ Vt,
                                                   u16* __restrict__ attn) {
  __shared__ __attribute__((aligned(16))) u16 Ks[64 * 64];   // [key][d], swizzled
  __shared__ __attribute__((aligned(16))) u16 Vs[64 * 64];   // [d][s],  swizzled
  int bid = blockIdx.x;
  int pp = bid >> 8, rrb = bid & 255;
  int h  = rrb >> 4;
  int jj = rrb & 15;
  int b  = pp;
  int qt = pp ? (15 - jj) : jj;   // CU c & c+256 -> complementary work
  int tid = threadIdx.x;
  int lane = tid & 63, w = tid >> 6;
  int l31 = lane & 31, hh = lane >> 5;
  int q0w = qt * 128 + w * 32;
  int q_abs = q0w + l31;

  // Q B-fragments: col=q (l31), k = ks*16 + hh*8 + j
  short8 qf[4];
  const u16* Qrow = qkv + (size_t)(b * T_ + q_abs) * NQKV_ + h * 64;
#pragma unroll
  for (int ks = 0; ks < 4; ks++) qf[ks] = *(const short8*)&Qrow[ks * 16 + hh * 8];

  const u16* Kbase  = qkv + (size_t)(b * T_) * NQKV_ + 1024 + h * 64;
  const u16* Vtbase = Vt + (size_t)(h * 64) * M_ + b * T_;

  // staging: 512 uint4 per matrix / 256 threads = 2 each
  int r0s = tid >> 3, c0s = tid & 7;           // rows 0..31
  int r1s = r0s + 32;                          // rows 32..63
  unsigned kd0 = (unsigned)((r0s * 128 + c0s * 16) ^ ((r0s & 7) << 4));
  unsigned kd1 = (unsigned)((r1s * 128 + c0s * 16) ^ ((r1s & 7) << 4));
  const u16* Kg0 = &Kbase[(size_t)r0s * NQKV_ + c0s * 8];
  const u16* Kg1 = &Kbase[(size_t)r1s * NQKV_ + c0s * 8];
  const u16* Vg0 = &Vtbase[(size_t)r0s * M_ + c0s * 8];
  const u16* Vg1 = &Vtbase[(size_t)r1s * M_ + c0s * 8];

  f32x16 o[2] = {};
  float m_run = -__builtin_inff(), l_run = 0.f;
  const float SCL = 0.03125f;  // E_^-0.5 (faithful: reference scales by C**-0.5)
  const int s_stop = qt * 128 + 128;

  // T14 prologue: tile 0 loads into regs
  uint4 kr0 = *(const uint4*)Kg0;
  uint4 kr1 = *(const uint4*)Kg1;
  uint4 vr0 = *(const uint4*)Vg0;
  uint4 vr1 = *(const uint4*)Vg1;

  for (int s0 = 0; s0 < s_stop; s0 += 64) {
    __syncthreads();                 // prev tile's LDS reads done
    *(uint4*)((char*)Ks + kd0) = kr0;
    *(uint4*)((char*)Ks + kd1) = kr1;
    *(uint4*)((char*)Vs + kd0) = vr0;
    *(uint4*)((char*)Vs + kd1) = vr1;
    if (s0 + 64 < s_stop) {          // issue next tile's loads (latency hides under compute)
      kr0 = *(const uint4*)&Kg0[(size_t)(s0 + 64) * NQKV_];
      kr1 = *(const uint4*)&Kg1[(size_t)(s0 + 64) * NQKV_];
      vr0 = *(const uint4*)&Vg0[s0 + 64];
      vr1 = *(const uint4*)&Vg1[s0 + 64];
    }
    __syncthreads();                 // staged tile visible
    if (s0 > q0w + 31) continue;     // tile fully masked for this wave (wave-uniform)

    // --- S^T = K @ Q^T : 2 key-chunks of 32, accumulate over 4 d-slices ---
    f32x16 st[2];
#pragma unroll
    for (int c = 0; c < 2; c++) {
      f32x16 acc = {};
      int key = c * 32 + l31;
#pragma unroll
      for (int ks = 0; ks < 4; ks++) {
        unsigned off = (unsigned)((key * 128 + ks * 32 + hh * 16) ^ ((key & 7) << 4));
        short8 kf = *(const short8*)((const char*)Ks + off);
        acc = __builtin_amdgcn_mfma_f32_32x32x16_bf16(kf, qf[ks], acc, 0, 0, 0);
      }
      st[c] = acc;
    }

    // --- mask (diagonal tiles only) + tile max, raw-score domain ---
    float tmax = -__builtin_inff();
    if (s0 + 63 > q0w) {
#pragma unroll
      for (int c = 0; c < 2; c++)
#pragma unroll
        for (int r = 0; r < 16; r++) {
          int key = s0 + c * 32 + (r & 3) + 8 * (r >> 2) + 4 * hh;
          float v = (key > q_abs) ? -__builtin_inff() : st[c][r];
          st[c][r] = v;
          tmax = fmaxf(tmax, v);
        }
    } else {
#pragma unroll
      for (int c = 0; c < 2; c++)
#pragma unroll
        for (int r = 0; r < 16; r++) tmax = fmaxf(tmax, st[c][r]);
    }
    tmax = fmaxf(tmax, __shfl_xor(tmax, 32));

    // --- T13 defer-max: rescale only when max grew > 8 p-exp units (256 raw) ---
    if (!__all(tmax - m_run <= 256.0f)) {
      float newm = fmaxf(m_run, tmax);
      float fac = __expf((m_run - newm) * SCL);
      l_run *= fac;
      o[0] *= fac;
      o[1] *= fac;
      m_run = newm;
    }
    float nm = -m_run * SCL;
    float psum = 0.f;
#pragma unroll
    for (int c = 0; c < 2; c++)
#pragma unroll
      for (int r = 0; r < 16; r++) {
        float pv = __expf(fmaf(st[c][r], SCL, nm));   // exp((s-m)*scale), <= e^8
        st[c][r] = pv;
        psum += pv;
      }
    psum += __shfl_xor(psum, 32);
    l_run += psum;

    // --- pack P to bf16 words: wds[c][2a+b2] = pack(p[4a+2b2], p[4a+2b2+1]) ---
    unsigned wds[2][8];
#pragma unroll
    for (int c = 0; c < 2; c++)
#pragma unroll
      for (int i = 0; i < 8; i++)
        wds[c][i] = pack2bf(st[c][2 * i], st[c][2 * i + 1]);

    // --- O^T += V^T @ P^T : 4 key-slices of 16, B-frag built in-register ---
#pragma unroll
    for (int ks16 = 0; ks16 < 4; ks16++) {
      int c = ks16 >> 1, e = ks16 & 1;
      // receiver needs quad a = 2e + hh from BOTH halves; sender ships the quad
      // the partner needs (hh=0 ships quad 2e+1, hh=1 ships quad 2e)
      unsigned send0 = hh ? wds[c][4 * e]     : wds[c][4 * e + 2];
      unsigned send1 = hh ? wds[c][4 * e + 1] : wds[c][4 * e + 3];
      unsigned recv0 = (unsigned)__shfl_xor((int)send0, 32);
      unsigned recv1 = (unsigned)__shfl_xor((int)send1, 32);
      uint4 fw;
      fw.x = hh ? recv0 : wds[c][4 * e];
      fw.y = hh ? recv1 : wds[c][4 * e + 1];
      fw.z = hh ? wds[c][4 * e + 2] : recv0;
      fw.w = hh ? wds[c][4 * e + 3] : recv1;
      short8 pf = __builtin_bit_cast(short8, fw);
#pragma unroll
      for (int dc = 0; dc < 2; dc++) {
        int d = dc * 32 + l31;
        unsigned off = (unsigned)((d * 128 + ks16 * 32 + hh * 16) ^ ((d & 7) << 4));
        short8 vf = *(const short8*)((const char*)Vs + off);
        o[dc] = __builtin_amdgcn_mfma_f32_32x32x16_bf16(vf, pf, o[dc], 0, 0, 0);
      }
    }
  }

  // --- epilogue: O^T col=q (l31), row d = dc*32 + 8a + 4hh + (r&3); store uint2 ---
  float inv = 1.f / l_run;
  const size_t orow = (size_t)(b * T_ + q_abs) * E_ + h * 64;
#pragma unroll
  for (int dc = 0; dc < 2; dc++)
#pragma unroll
    for (int a = 0; a < 4; a++) {
      uint2 r;
      r.x = pack2bf(o[dc][4 * a] * inv, o[dc][4 * a + 1] * inv);
      r.y = pack2bf(o[dc][4 * a + 2] * inv, o[dc][4 * a + 3] * inv);
      *(uint2*)&attn[orow + dc * 32 + 8 * a + 4 * hh] = r;
    }
}

// ---------------- launch ----------------
extern "C" void kernel_launch(void* const* d_in, const int* in_sizes, int n_in,
                              void* d_out, int out_size, void* d_ws, size_t ws_size,
                              hipStream_t stream) {
  const float* x  = (const float*)d_in[0];
  const float* Wq = (const float*)d_in[1];
  const float* Wk = (const float*)d_in[2];
  const float* Wv = (const float*)d_in[3];
  const float* Wo = (const float*)d_in[4];
  const float* bo = (const float*)d_in[5];
  const float* W1 = (const float*)d_in[6];
  const float* b1 = (const float*)d_in[7];
  const float* W2 = (const float*)d_in[8];
  const float* b2 = (const float*)d_in[9];
  float* out = (float*)d_out;

  const size_t MB = 1048576;
  char* ws = (char*)d_ws;
  u16* xb    = (u16*)(ws + 0);          // 8MB   (x1b aliases after QKV GEMM)
  u16* WqkvT = (u16*)(ws + 8 * MB);     // 6MB   [3072][1024]
  u16* WoT   = (u16*)(ws + 14 * MB);    // 2MB
  u16* W1T   = (u16*)(ws + 16 * MB);    // 8MB
  u16* W2T   = (u16*)(ws + 24 * MB);    // 8MB
  u16* qkv   = (u16*)(ws + 32 * MB);    // 24MB  [4096][3072] (dead after attn)
  u16* attn  = (u16*)(ws + 56 * MB);    // 8MB   (dead after proj)
  float* x1  = (float*)(ws + 64 * MB);  // 16MB  (written by proj, after Vt dead)
  u16* Vtb   = (u16*)(ws + 64 * MB);    // 8MB   overlaps x1 (dead before x1 written)
  u16* x1b   = (u16*)(ws + 0);          // alias xb
  u16* hbuf  = (u16*)(ws + 32 * MB);    // 32MB  alias qkv+attn (dead after proj)

  // prep: cast + weight transposes to [N][K] bf16
  cast_bf16_kernel<<<(M_ * E_ / 4 + 255) / 256, 256, 0, stream>>>(x, xb, M_ * E_ / 4);
  transpose_cast_kernel<<<dim3(2, 32, 16),  256, 0, stream>>>(Wq, WqkvT,                E_, D_, E_);
  transpose_cast_kernel<<<dim3(2, 32, 16),  256, 0, stream>>>(Wk, WqkvT + 1024 * 1024,  E_, D_, E_);
  transpose_cast_kernel<<<dim3(2, 32, 16),  256, 0, stream>>>(Wv, WqkvT + 2048 * 1024,  E_, D_, E_);
  transpose_cast_kernel<<<dim3(32, 32, 1),  256, 0, stream>>>(Wo, WoT, E_, E_, E_);
  transpose_cast_kernel<<<dim3(128, 32, 1), 256, 0, stream>>>(W1, W1T, E_, DF_, E_);
  transpose_cast_kernel<<<dim3(32, 128, 1), 256, 0, stream>>>(W2, W2T, DF_, E_, DF_);

  // fused QKV GEMM: qkv[M][3072]
  gemm_bt<128,false,false,false,false,true><<<dim3(NQKV_ / 128, M_ / 128), 256, 0, stream>>>(
      xb, WqkvT, M_, NQKV_, E_, nullptr, nullptr, nullptr, qkv);

  // V -> V^T  (qkv cols 2048..3071 -> Vt[E][M])
  transpose_u16_kernel<<<dim3(E_ / 64, M_ / 64), 256, 0, stream>>>(qkv + 2048, Vtb, M_, E_, NQKV_);

  attn_kernel<<<B_ * H_ * (T_ / 128), 256, 0, stream>>>(qkv, Vtb, attn);

  // x1 = x + attn @ Wo + bo   (fp32 + bf16 mirror); TM=64 -> 512 blocks
  gemm_bt<64,true,false,true,true,true><<<dim3(E_ / 128, M_ / 64), 256, 0, stream>>>(
      attn, WoT, M_, E_, E_, bo, x, x1, x1b);
  // h = relu(x1 @ W1 + b1)
  gemm_bt<128,true,true,false,false,true><<<dim3(DF_ / 128, M_ / 128), 256, 0, stream>>>(
      x1b, W1T, M_, DF_, E_, b1, nullptr, nullptr, hbuf);
  // out = x1 + h @ W2 + b2 ; TM=64 -> 512 blocks
  gemm_bt<64,true,false,true,true,false><<<dim3(E_ / 128, M_ / 64), 256, 0, stream>>>(
      hbuf, W2T, M_, E_, DF_, b2, x1, out, nullptr);
}